// Round 1
// 1211.464 us; speedup vs baseline: 1.3236x; 1.3236x over previous
//
#include <hip/hip_runtime.h>
#include <cstdint>
#include <cstddef>

namespace {

constexpr int T = 10;
constexpr int N = 50000;
constexpr int R = 50000;
constexpr int DIN = 128;
constexpr int D = 64;
constexpr int E = 400000;

// LDS-binned edge-prep geometry
constexpr int BINS = 8192;              // bins per range (LDS-resident, 32 KB packed)
constexpr int NR = 7;                   // ranges: 7*8192 = 57344 >= N
constexpr int SEG = 16;                 // edge segments per t (1120 blocks total)
constexpr int ESEG = E / SEG;           // 25000 edges per segment
constexpr int EV4 = ESEG / 4;           // 6250 int4 groups per segment

// hist packing: count in bits [24..31], weight-sum fixed-point 2^-18 in bits [0..23]
constexpr float WSCALE = 262144.0f;     // 2^18
constexpr float WINV = 1.0f / 262144.0f;

typedef __attribute__((ext_vector_type(8))) short bf16x8;
typedef __attribute__((ext_vector_type(4))) float f32x4;

__device__ __forceinline__ float bf2f(unsigned short u) {
  return __uint_as_float(((unsigned)u) << 16);
}
__device__ __forceinline__ unsigned short f2bf(float f) {
  unsigned u = __float_as_uint(f);
  return (unsigned short)((u + 0x7FFFu + ((u >> 16) & 1u)) >> 16);
}

// ---------------------------------------------------------------- pass A: LDS histogram (packed u32)
// block = (t, range, seg). 32 KB LDS -> 5 blocks/CU. int4/float4 edge loads.
__global__ __launch_bounds__(256) void k_hist(const int* __restrict__ ei,
                                              const float* __restrict__ ew,
                                              unsigned* __restrict__ pu) {
  __shared__ unsigned h[BINS];
  int b = blockIdx.x;
  int s = b % SEG;
  int tr = b / SEG;
  int r = tr % NR;
  int t = tr / NR;
  for (int i = threadIdx.x; i < BINS; i += 256) h[i] = 0u;
  __syncthreads();
  int bin0 = r * BINS;
  const int4* dst4 = (const int4*)(ei + (size_t)t * 2 * E + E + s * ESEG);
  const float4* ew4 = (const float4*)(ew + (size_t)t * E + s * ESEG);
  for (int i = threadIdx.x; i < EV4; i += 256) {
    int4 d = dst4[i];
    float4 w = ew4[i];
    unsigned a0 = (unsigned)(d.x - bin0);
    unsigned a1 = (unsigned)(d.y - bin0);
    unsigned a2 = (unsigned)(d.z - bin0);
    unsigned a3 = (unsigned)(d.w - bin0);
    if (a0 < (unsigned)BINS) atomicAdd(&h[a0], 0x1000000u + (unsigned)fmaf(w.x, WSCALE, 0.5f));
    if (a1 < (unsigned)BINS) atomicAdd(&h[a1], 0x1000000u + (unsigned)fmaf(w.y, WSCALE, 0.5f));
    if (a2 < (unsigned)BINS) atomicAdd(&h[a2], 0x1000000u + (unsigned)fmaf(w.z, WSCALE, 0.5f));
    if (a3 < (unsigned)BINS) atomicAdd(&h[a3], 0x1000000u + (unsigned)fmaf(w.w, WSCALE, 0.5f));
  }
  __syncthreads();
  size_t base = (size_t)b * BINS;
  for (int i = threadIdx.x; i < BINS; i += 256) pu[base + i] = h[i];
}

// ---------------------------------------------------------------- pass B: reduce partials -> cnt, dinv
__global__ __launch_bounds__(256) void k_hreduce(const unsigned* __restrict__ pu,
                                                 int* __restrict__ cnt,
                                                 float* __restrict__ dinv) {
  int i = blockIdx.x * 256 + threadIdx.x;
  if (i >= T * N) return;
  int t = i / N, n = i - t * N;
  int r = n / BINS, rel = n - r * BINS;
  unsigned c = 0;
  unsigned wsum = 0;
  #pragma unroll
  for (int s = 0; s < SEG; ++s) {
    unsigned v = pu[((size_t)((t * NR + r) * SEG + s)) * BINS + rel];
    c += v >> 24;
    wsum += v & 0xFFFFFFu;
  }
  cnt[i] = (int)c;
  dinv[i] = rsqrtf(1.0f + (float)wsum * WINV);  // deg = 1 (self) + sum(ew)
}

// per-t exclusive scan of cnt -> rowptr (one block per t, 4 elems/thread)
__global__ __launch_bounds__(256) void k_scan(const int* __restrict__ cnt,
                                              int* __restrict__ rowptr) {
  int t = blockIdx.x;
  int lane = threadIdx.x & 63, wid = threadIdx.x >> 6;
  __shared__ int wsum[4];
  __shared__ int carry_s;
  if (threadIdx.x == 0) carry_s = 0;
  __syncthreads();
  const int4* cp = (const int4*)(cnt + (size_t)t * N);
  int4* rp = (int4*)(rowptr + (size_t)t * N);
  constexpr int NI4 = N / 4;  // 12500
  for (int base = 0; base < NI4; base += 256) {
    int i = base + threadIdx.x;
    int4 v = make_int4(0, 0, 0, 0);
    if (i < NI4) v = cp[i];
    int tot = v.x + v.y + v.z + v.w;
    int s = tot;
    #pragma unroll
    for (int off = 1; off < 64; off <<= 1) {
      int u = __shfl_up(s, off, 64);
      if (lane >= off) s += u;
    }
    if (lane == 63) wsum[wid] = s;
    int carry = carry_s;
    __syncthreads();
    int wadd = 0;
    #pragma unroll
    for (int w = 0; w < 4; ++w) if (w < wid) wadd += wsum[w];
    if (i < NI4) {
      int excl = carry + wadd + s - tot;
      int4 o;
      o.x = excl;
      o.y = excl + v.x;
      o.z = o.y + v.y;
      o.w = o.z + v.z;
      rp[i] = o;
    }
    __syncthreads();
    if (threadIdx.x == 0) carry_s = carry + wsum[0] + wsum[1] + wsum[2] + wsum[3];
    __syncthreads();
  }
}

// ---------------------------------------------------------------- pass C: partial counts -> absolute seg cursors (in place)
__global__ __launch_bounds__(256) void k_segoff(unsigned* __restrict__ pu,
                                                const int* __restrict__ rowptr) {
  int i = blockIdx.x * 256 + threadIdx.x;
  if (i >= T * N) return;
  int t = i / N, n = i - t * N;
  int r = n / BINS, rel = n - r * BINS;
  unsigned run = (unsigned)rowptr[i];
  #pragma unroll
  for (int s = 0; s < SEG; ++s) {
    size_t base = ((size_t)((t * NR + r) * SEG + s)) * BINS + rel;
    unsigned v = pu[base];
    pu[base] = run;
    run += v >> 24;
  }
}

// ---------------------------------------------------------------- pass D: place packed (src, raw ew) via LDS cursors
// dinv[src] folded into the GEMM epilogue (MODE 2) -> no dependent gather here.
__global__ __launch_bounds__(256) void k_fill2(const int* __restrict__ ei,
                                               const float* __restrict__ ew,
                                               const unsigned* __restrict__ pu,
                                               int2* __restrict__ pk) {
  __shared__ int cur[BINS];
  int b = blockIdx.x;
  int s = b % SEG;
  int tr = b / SEG;
  int r = tr % NR;
  int t = tr / NR;
  size_t pbase = (size_t)b * BINS;
  for (int i = threadIdx.x; i < BINS; i += 256) cur[i] = (int)pu[pbase + i];
  __syncthreads();
  int bin0 = r * BINS;
  const int4* src4 = (const int4*)(ei + (size_t)t * 2 * E + s * ESEG);
  const int4* dst4 = (const int4*)(ei + (size_t)t * 2 * E + E + s * ESEG);
  const float4* ew4 = (const float4*)(ew + (size_t)t * E + s * ESEG);
  int2* pkt = pk + (size_t)t * E;
  for (int i = threadIdx.x; i < EV4; i += 256) {
    int4 d = dst4[i];
    int4 sv = src4[i];
    float4 w = ew4[i];
    unsigned a0 = (unsigned)(d.x - bin0);
    unsigned a1 = (unsigned)(d.y - bin0);
    unsigned a2 = (unsigned)(d.z - bin0);
    unsigned a3 = (unsigned)(d.w - bin0);
    if (a0 < (unsigned)BINS) {
      int pos = atomicAdd(&cur[a0], 1);
      pkt[pos] = make_int2(sv.x, __float_as_int(w.x));
    }
    if (a1 < (unsigned)BINS) {
      int pos = atomicAdd(&cur[a1], 1);
      pkt[pos] = make_int2(sv.y, __float_as_int(w.y));
    }
    if (a2 < (unsigned)BINS) {
      int pos = atomicAdd(&cur[a2], 1);
      pkt[pos] = make_int2(sv.z, __float_as_int(w.z));
    }
    if (a3 < (unsigned)BINS) {
      int pos = atomicAdd(&cur[a3], 1);
      pkt[pos] = make_int2(sv.w, __float_as_int(w.w));
    }
  }
}

// ---------------------------------------------------------------- weight prep: fp32 -> bf16 into one buffer
__global__ __launch_bounds__(256) void k_prep(const float* __restrict__ g1w,
                                              const float* __restrict__ g2w,
                                              const float* __restrict__ inw,
                                              const float* __restrict__ outw,
                                              const float* __restrict__ fcw,
                                              unsigned short* __restrict__ Wb) {
  int i = blockIdx.x * 256 + threadIdx.x;
  if (i >= 32768) return;
  const float* src;
  int off;
  if (i < 8192)       { src = g1w;  off = 0; }
  else if (i < 12288) { src = g2w;  off = 8192; }
  else if (i < 24576) { src = inw;  off = 12288; }
  else if (i < 28672) { src = outw; off = 24576; }
  else                { src = fcw;  off = 28672; }
  Wb[i] = f2bf(src[i - off]);
}

// ---------------------------------------------------------------- MFMA GEMM: out[m][j] = sum_k W[j][k] * B[m][k]
// A = weight rows (M-dim = output feature j), B = data rows (N-dim = m). C/D layout
// (16x16x32): col = lane&15 -> m; row = quad*4+reg -> j: lane owns 4 consecutive
// features of one row -> b64 bf16 store, no transpose.
// MODE 0: plain bf16 out.  MODE 1: +bias, split q9/kv.  MODE 2: row-scale by biasp[m] (dinv).
template <int K, int NT, bool BF16B, int MODE>
__global__ __launch_bounds__(256) void k_mm(const unsigned short* __restrict__ Wb,
                                            const void* __restrict__ Bv,
                                            const float* __restrict__ biasp,
                                            unsigned short* __restrict__ out,
                                            unsigned short* __restrict__ q9,
                                            int Mwaves) {
  int wv = threadIdx.x >> 6, lane = threadIdx.x & 63;
  int wave = blockIdx.x * 4 + wv;
  if (wave >= Mwaves) return;
  int m0 = wave * 16;
  int half = lane & 15, quad = lane >> 4;
  constexpr int KS = K / 32;
  int m = m0 + half;
  float ds = 1.0f;
  if (MODE == 2) ds = biasp[m];
  bf16x8 bfrag[KS];
  if (BF16B) {
    const unsigned short* Bp = (const unsigned short*)Bv + (size_t)m * K + quad * 8;
    #pragma unroll
    for (int ks = 0; ks < KS; ++ks) bfrag[ks] = *(const bf16x8*)(Bp + ks * 32);
  } else {
    const float* Bp = (const float*)Bv + (size_t)m * K + quad * 8;
    #pragma unroll
    for (int ks = 0; ks < KS; ++ks) {
      float4 f0 = *(const float4*)(Bp + ks * 32);
      float4 f1 = *(const float4*)(Bp + ks * 32 + 4);
      bf16x8 b;
      b[0] = (short)f2bf(f0.x); b[1] = (short)f2bf(f0.y);
      b[2] = (short)f2bf(f0.z); b[3] = (short)f2bf(f0.w);
      b[4] = (short)f2bf(f1.x); b[5] = (short)f2bf(f1.y);
      b[6] = (short)f2bf(f1.z); b[7] = (short)f2bf(f1.w);
      bfrag[ks] = b;
    }
  }
  #pragma unroll
  for (int jt = 0; jt < NT; ++jt) {
    f32x4 acc = {0.f, 0.f, 0.f, 0.f};
    const unsigned short* Wp = Wb + (size_t)(jt * 16 + half) * K + quad * 8;
    #pragma unroll
    for (int ks = 0; ks < KS; ++ks) {
      bf16x8 afrag = *(const bf16x8*)(Wp + ks * 32);
      acc = __builtin_amdgcn_mfma_f32_16x16x32_bf16(afrag, bfrag[ks], acc, 0, 0, 0);
    }
    int j = jt * 16 + quad * 4;
    if (MODE == 1) {
      float4 b4 = *(const float4*)(biasp + j);
      acc[0] += b4.x; acc[1] += b4.y; acc[2] += b4.z; acc[3] += b4.w;
    }
    if (MODE == 2) {
      acc[0] *= ds; acc[1] *= ds; acc[2] *= ds; acc[3] *= ds;
    }
    ushort4 o;
    o.x = f2bf(acc[0]); o.y = f2bf(acc[1]); o.z = f2bf(acc[2]); o.w = f2bf(acc[3]);
    if (MODE != 1) {
      *(ushort4*)(out + (size_t)m * (NT * 16) + j) = o;
    } else {
      if (jt < 4) {
        if (m % 10 == 9) *(ushort4*)(q9 + (size_t)(m / 10) * 64 + j) = o;
      } else {
        *(ushort4*)(out + (size_t)m * 128 + (j - 64)) = o;
      }
    }
  }
}

// ---------------------------------------------------------------- GCN aggregation (gather over CSR)
// hw rows are pre-scaled by dinv[src]; pk holds raw ew. out = dn*(acc + hw'[n]) + b.
template <bool SCATTER>
__global__ __launch_bounds__(256) void k_gather(
    const unsigned short* __restrict__ hw, const int2* __restrict__ pk,
    const float* __restrict__ dinv, const int* __restrict__ rowptr,
    const int* __restrict__ cnt, const float* __restrict__ bias,
    const int* __restrict__ gidx, unsigned short* __restrict__ outp) {
  int wv = threadIdx.x >> 6, lane = threadIdx.x & 63;
  long long wave = (long long)blockIdx.x * 4 + wv;
  if (wave >= (long long)T * N) return;
  int t = (int)(wave / N);
  int n = (int)(wave - (long long)t * N);
  const unsigned short* hwt = hw + (size_t)t * N * D;
  const int2* pkt = pk + (size_t)t * E;
  float dn = dinv[t * N + n];
  int start = rowptr[t * N + n];
  int m = cnt[t * N + n];
  int grp = lane >> 4, sub = lane & 15;
  float4 acc0 = make_float4(0.f, 0.f, 0.f, 0.f);
  float4 acc1 = make_float4(0.f, 0.f, 0.f, 0.f);
  for (int b = 0; b < m; b += 64) {
    int mm = min(64, m - b);
    int2 rec = make_int2(0, 0);
    if (lane < mm) rec = pkt[start + b + lane];
    int s_l = rec.x;
    float w_l = __int_as_float(rec.y);
    int iters = (mm + 3) >> 2;
    int i = 0;
    for (; i + 2 <= iters; i += 2) {
      int i0 = 4 * i + grp;
      int i1 = i0 + 4;
      int sa = __shfl(s_l, i0, 64);
      float wa = __shfl(w_l, i0, 64);
      int sb = __shfl(s_l, i1, 64);
      float wb = __shfl(w_l, i1, 64);
      ushort4 ha = *(const ushort4*)(hwt + (size_t)sa * D + (sub << 2));
      ushort4 hb = *(const ushort4*)(hwt + (size_t)sb * D + (sub << 2));
      acc0.x = fmaf(wa, bf2f(ha.x), acc0.x);
      acc0.y = fmaf(wa, bf2f(ha.y), acc0.y);
      acc0.z = fmaf(wa, bf2f(ha.z), acc0.z);
      acc0.w = fmaf(wa, bf2f(ha.w), acc0.w);
      acc1.x = fmaf(wb, bf2f(hb.x), acc1.x);
      acc1.y = fmaf(wb, bf2f(hb.y), acc1.y);
      acc1.z = fmaf(wb, bf2f(hb.z), acc1.z);
      acc1.w = fmaf(wb, bf2f(hb.w), acc1.w);
    }
    if (i < iters) {
      int i0 = 4 * i + grp;
      int sa = __shfl(s_l, i0, 64);
      float wa = __shfl(w_l, i0, 64);
      ushort4 ha = *(const ushort4*)(hwt + (size_t)sa * D + (sub << 2));
      acc0.x = fmaf(wa, bf2f(ha.x), acc0.x);
      acc0.y = fmaf(wa, bf2f(ha.y), acc0.y);
      acc0.z = fmaf(wa, bf2f(ha.z), acc0.z);
      acc0.w = fmaf(wa, bf2f(ha.w), acc0.w);
    }
  }
  acc0.x += acc1.x; acc0.y += acc1.y; acc0.z += acc1.z; acc0.w += acc1.w;
  acc0.x += __shfl_xor(acc0.x, 16, 64); acc0.x += __shfl_xor(acc0.x, 32, 64);
  acc0.y += __shfl_xor(acc0.y, 16, 64); acc0.y += __shfl_xor(acc0.y, 32, 64);
  acc0.z += __shfl_xor(acc0.z, 16, 64); acc0.z += __shfl_xor(acc0.z, 32, 64);
  acc0.w += __shfl_xor(acc0.w, 16, 64); acc0.w += __shfl_xor(acc0.w, 32, 64);
  if (grp == 0) {
    ushort4 sv = *(const ushort4*)(hwt + (size_t)n * D + (sub << 2));
    float4 b4 = *(const float4*)(bias + (sub << 2));
    float vx = fmaxf(fmaf(dn, acc0.x + bf2f(sv.x), b4.x), 0.f);
    float vy = fmaxf(fmaf(dn, acc0.y + bf2f(sv.y), b4.y), 0.f);
    float vz = fmaxf(fmaf(dn, acc0.z + bf2f(sv.z), b4.z), 0.f);
    float vw = fmaxf(fmaf(dn, acc0.w + bf2f(sv.w), b4.w), 0.f);
    ushort4 o;
    o.x = f2bf(vx); o.y = f2bf(vy); o.z = f2bf(vz); o.w = f2bf(vw);
    size_t ro;
    if (SCATTER) {
      int rr = gidx[(size_t)t * R + n];
      ro = ((size_t)rr * T + t) * D;
    } else {
      ro = ((size_t)t * N + n) * D;
    }
    *(ushort4*)(outp + ro + (sub << 2)) = o;
  }
}

// ---------------------------------------------------------------- attention core: one wave per r
__global__ __launch_bounds__(256) void k_attn2(const unsigned short* __restrict__ kv,
                                               const unsigned short* __restrict__ q9,
                                               unsigned short* __restrict__ ao) {
  int wv = threadIdx.x >> 6, lane = threadIdx.x & 63;
  int r = blockIdx.x * 4 + wv;
  if (r >= R) return;
  float qv = bf2f(q9[(size_t)r * 64 + lane]);
  const unsigned short* kvr = kv + (size_t)r * T * 128;
  float sc[T], vv[T];
  #pragma unroll
  for (int s = 0; s < T; ++s) {
    float kk = bf2f(kvr[s * 128 + lane]);
    vv[s] = bf2f(kvr[s * 128 + 64 + lane]);
    float p = qv * kk;
    p += __shfl_xor(p, 8, 16);
    p += __shfl_xor(p, 4, 16);
    p += __shfl_xor(p, 2, 16);
    p += __shfl_xor(p, 1, 16);
    sc[s] = p * 0.25f;  // 1/sqrt(16)
  }
  float mx = sc[0];
  #pragma unroll
  for (int s = 1; s < T; ++s) mx = fmaxf(mx, sc[s]);
  float ssum = 0.f;
  #pragma unroll
  for (int s = 0; s < T; ++s) { sc[s] = expf(sc[s] - mx); ssum += sc[s]; }
  float rinv = 1.0f / ssum;
  float aov = 0.f;
  #pragma unroll
  for (int s = 0; s < T; ++s) aov = fmaf(sc[s] * rinv, vv[s], aov);
  ao[(size_t)r * 64 + lane] = f2bf(aov);
}

// ---------------------------------------------------------------- LN1
__global__ __launch_bounds__(256) void k_ln1(const unsigned short* __restrict__ te,
                                             const unsigned short* __restrict__ proj,
                                             const float* __restrict__ outB,
                                             const float* __restrict__ w1,
                                             const float* __restrict__ w2,
                                             const float* __restrict__ g1,
                                             const float* __restrict__ b1,
                                             float* __restrict__ finf,
                                             unsigned short* __restrict__ finb) {
  int wv = threadIdx.x >> 6, lane = threadIdx.x & 63;
  int r = blockIdx.x * 4 + wv;
  if (r >= R) return;
  float t9 = bf2f(te[((size_t)r * T + (T - 1)) * 64 + lane]);
  float pr = bf2f(proj[(size_t)r * 64 + lane]) + outB[lane];
  float pre = w1[(T - 1) * 64 + lane] * t9 + w2[(T - 1) * 64 + lane] * pr;
  float s1 = pre;
  #pragma unroll
  for (int off = 32; off >= 1; off >>= 1) s1 += __shfl_xor(s1, off, 64);
  float mu = s1 * (1.0f / 64.0f);
  float dv = pre - mu;
  float s2 = dv * dv;
  #pragma unroll
  for (int off = 32; off >= 1; off >>= 1) s2 += __shfl_xor(s2, off, 64);
  float rstd = 1.0f / sqrtf(s2 * (1.0f / 64.0f) + 1e-5f);
  float fin = dv * rstd * g1[lane] + b1[lane];
  finf[(size_t)r * 64 + lane] = fin;
  finb[(size_t)r * 64 + lane] = f2bf(fin);
}

// ---------------------------------------------------------------- LN2
__global__ __launch_bounds__(256) void k_ln2(const float* __restrict__ finf,
                                             const unsigned short* __restrict__ o2,
                                             const float* __restrict__ fcB,
                                             const float* __restrict__ w3,
                                             const float* __restrict__ w4,
                                             const float* __restrict__ g2,
                                             const float* __restrict__ b2,
                                             float* __restrict__ out) {
  int wv = threadIdx.x >> 6, lane = threadIdx.x & 63;
  int r = blockIdx.x * 4 + wv;
  if (r >= R) return;
  float fin = finf[(size_t)r * 64 + lane];
  float oo = bf2f(o2[(size_t)r * 64 + lane]) + fcB[lane];
  float pre = w3[lane] * fin + w4[lane] * oo;
  float s1 = pre;
  #pragma unroll
  for (int off = 32; off >= 1; off >>= 1) s1 += __shfl_xor(s1, off, 64);
  float mu = s1 * (1.0f / 64.0f);
  float dv = pre - mu;
  float s2 = dv * dv;
  #pragma unroll
  for (int off = 32; off >= 1; off >>= 1) s2 += __shfl_xor(s2, off, 64);
  float rstd = 1.0f / sqrtf(s2 * (1.0f / 64.0f) + 1e-5f);
  out[(size_t)r * 64 + lane] = dv * rstd * g2[lane] + b2[lane];
}

}  // namespace

extern "C" void kernel_launch(void* const* d_in, const int* in_sizes, int n_in,
                              void* d_out, int out_size, void* d_ws, size_t ws_size,
                              hipStream_t stream) {
  const float* x      = (const float*)d_in[0];
  const int*   ei     = (const int*)d_in[1];
  const float* ew     = (const float*)d_in[2];
  const int*   gidx   = (const int*)d_in[3];
  const float* gcn1_w = (const float*)d_in[4];
  const float* gcn1_b = (const float*)d_in[5];
  const float* gcn2_w = (const float*)d_in[6];
  const float* gcn2_b = (const float*)d_in[7];
  const float* in_w   = (const float*)d_in[8];
  const float* in_b   = (const float*)d_in[9];
  const float* out_w  = (const float*)d_in[10];
  const float* out_b  = (const float*)d_in[11];
  const float* w1     = (const float*)d_in[12];
  const float* w2     = (const float*)d_in[13];
  const float* w3     = (const float*)d_in[14];
  const float* w4     = (const float*)d_in[15];
  const float* ln1_g  = (const float*)d_in[16];
  const float* ln1_b  = (const float*)d_in[17];
  const float* ln2_g  = (const float*)d_in[18];
  const float* ln2_b  = (const float*)d_in[19];
  const float* fc_w   = (const float*)d_in[20];
  const float* fc_b   = (const float*)d_in[21];
  float* outp = (float*)d_out;

  char* ws = (char*)d_ws;
  size_t off = 0;
  auto alloc = [&](size_t bytes) {
    void* p = ws + off;
    off += (bytes + 255) & ~(size_t)255;
    return p;
  };
  // persistent-tail region (~109 MB)
  unsigned short* h1te = (unsigned short*)alloc(sizeof(short) * (size_t)T * N * D);  // h1 / time_embeds
  unsigned short* q9b  = (unsigned short*)alloc(sizeof(short) * (size_t)R * D);
  unsigned short* aob  = (unsigned short*)alloc(sizeof(short) * (size_t)R * D);
  unsigned short* proj = (unsigned short*)alloc(sizeof(short) * (size_t)R * D);
  float*          finf = (float*)alloc(sizeof(float) * (size_t)R * D);
  unsigned short* finb = (unsigned short*)alloc(sizeof(short) * (size_t)R * D);
  unsigned short* o2b  = (unsigned short*)alloc(sizeof(short) * (size_t)R * D);
  unsigned short* Wb   = (unsigned short*)alloc(sizeof(short) * 32768);
  // union region: graph-prep (dead after fill2/gather2) aliased with kv (live after)
  size_t u_base = off;
  float* dinv   = (float*)alloc(sizeof(float) * T * N);
  int*   cnt    = (int*)alloc(sizeof(int) * T * N);
  int*   rowptr = (int*)alloc(sizeof(int) * T * N);
  int2*  pk     = (int2*)alloc(sizeof(int2) * (size_t)T * E);
  size_t pu_off = off;
  unsigned* pu  = (unsigned*)alloc(sizeof(unsigned) * (size_t)T * NR * SEG * BINS);  // 36.7 MB
  // hw aliases pu (pu dead after k_fill2; hw first written at GCN1 k_mm) and extends beyond
  unsigned short* hw = (unsigned short*)(ws + pu_off);
  size_t hw_end = pu_off + sizeof(short) * (size_t)T * N * D;
  if (hw_end > off) off = hw_end;
  // kv aliases the whole union region (everything above dead after gather2)
  unsigned short* kv = (unsigned short*)(ws + u_base);  // [T*N][128] bf16 = 128 MB
  size_t kv_end = u_base + sizeof(short) * (size_t)T * N * 128;
  if (kv_end > off) off = kv_end;

  const unsigned short* W1b = Wb;           // gcn1_w  [64][128]
  const unsigned short* W2b = Wb + 8192;    // gcn2_w  [64][64]
  const unsigned short* WIb = Wb + 12288;   // in_w    [192][64]
  const unsigned short* WOb = Wb + 24576;   // out_w   [64][64]
  const unsigned short* WFb = Wb + 28672;   // fc_w    [64][64]

  const int M = T * N;
  const int MW = M / 16;   // 31250
  const int RW = R / 16;   // 3125
  const int PREP_BLOCKS = T * NR * SEG;  // 1120

  // graph prep — no global atomics
  k_hist<<<PREP_BLOCKS, 256, 0, stream>>>(ei, ew, pu);
  k_hreduce<<<(T * N + 255) / 256, 256, 0, stream>>>(pu, cnt, dinv);
  k_scan<<<T, 256, 0, stream>>>(cnt, rowptr);
  k_segoff<<<(T * N + 255) / 256, 256, 0, stream>>>(pu, rowptr);
  k_fill2<<<PREP_BLOCKS, 256, 0, stream>>>(ei, ew, pu, pk);
  k_prep<<<128, 256, 0, stream>>>(gcn1_w, gcn2_w, in_w, out_w, fc_w, Wb);

  // GCN stage (hw rows pre-scaled by dinv via MODE 2)
  k_mm<DIN, 4, false, 2><<<(MW + 3) / 4, 256, 0, stream>>>(W1b, x, dinv, hw, nullptr, MW);
  k_gather<false><<<(M + 3) / 4, 256, 0, stream>>>(hw, pk, dinv, rowptr, cnt, gcn1_b,
                                                   nullptr, h1te);
  k_mm<D, 4, true, 2><<<(MW + 3) / 4, 256, 0, stream>>>(W2b, h1te, dinv, hw, nullptr, MW);
  k_gather<true><<<(M + 3) / 4, 256, 0, stream>>>(hw, pk, dinv, rowptr, cnt, gcn2_b,
                                                  gidx, h1te);  // -> time_embeds (bf16)

  // attention tail
  k_mm<D, 12, true, 1><<<(MW + 3) / 4, 256, 0, stream>>>(WIb, h1te, in_b, kv, q9b, MW);
  k_attn2<<<(R + 3) / 4, 256, 0, stream>>>(kv, q9b, aob);
  k_mm<D, 4, true, 0><<<(RW + 3) / 4, 256, 0, stream>>>(WOb, aob, nullptr, proj, nullptr, RW);
  k_ln1<<<(R + 3) / 4, 256, 0, stream>>>(h1te, proj, out_b, w1, w2, ln1_g, ln1_b, finf, finb);
  k_mm<D, 4, true, 0><<<(RW + 3) / 4, 256, 0, stream>>>(WFb, finb, nullptr, o2b, nullptr, RW);
  k_ln2<<<(R + 3) / 4, 256, 0, stream>>>(finf, o2b, fc_b, w3, w4, ln2_g, ln2_b, outp);
}

// Round 2
// 1193.991 us; speedup vs baseline: 1.3430x; 1.0146x over previous
//
#include <hip/hip_runtime.h>
#include <cstdint>
#include <cstddef>

namespace {

constexpr int T = 10;
constexpr int N = 50000;
constexpr int R = 50000;
constexpr int DIN = 128;
constexpr int D = 64;
constexpr int E = 400000;

// LDS-binned edge-prep geometry
constexpr int BINS = 8192;              // bins per range (LDS-resident, 32 KB packed)
constexpr int NR = 7;                   // ranges: 7*8192 = 57344 >= N
constexpr int SEG = 16;                 // edge segments per t (1120 blocks total)
constexpr int ESEG = E / SEG;           // 25000 edges per segment
constexpr int EV4 = ESEG / 4;           // 6250 int4 groups per segment

// hist packing: count in bits [24..31], weight-sum fixed-point 2^-18 in bits [0..23]
constexpr float WSCALE = 262144.0f;     // 2^18
constexpr float WINV = 1.0f / 262144.0f;

typedef _Float16 h16;
typedef __attribute__((ext_vector_type(8))) _Float16 f16x8;
typedef __attribute__((ext_vector_type(4))) _Float16 f16x4;
typedef __attribute__((ext_vector_type(4))) float f32x4;

// ---------------------------------------------------------------- pass A: LDS histogram (packed u32)
__global__ __launch_bounds__(256) void k_hist(const int* __restrict__ ei,
                                              const float* __restrict__ ew,
                                              unsigned* __restrict__ pu) {
  __shared__ unsigned h[BINS];
  int b = blockIdx.x;
  int s = b % SEG;
  int tr = b / SEG;
  int r = tr % NR;
  int t = tr / NR;
  for (int i = threadIdx.x; i < BINS; i += 256) h[i] = 0u;
  __syncthreads();
  int bin0 = r * BINS;
  const int4* dst4 = (const int4*)(ei + (size_t)t * 2 * E + E + s * ESEG);
  const float4* ew4 = (const float4*)(ew + (size_t)t * E + s * ESEG);
  for (int i = threadIdx.x; i < EV4; i += 256) {
    int4 d = dst4[i];
    float4 w = ew4[i];
    unsigned a0 = (unsigned)(d.x - bin0);
    unsigned a1 = (unsigned)(d.y - bin0);
    unsigned a2 = (unsigned)(d.z - bin0);
    unsigned a3 = (unsigned)(d.w - bin0);
    if (a0 < (unsigned)BINS) atomicAdd(&h[a0], 0x1000000u + (unsigned)fmaf(w.x, WSCALE, 0.5f));
    if (a1 < (unsigned)BINS) atomicAdd(&h[a1], 0x1000000u + (unsigned)fmaf(w.y, WSCALE, 0.5f));
    if (a2 < (unsigned)BINS) atomicAdd(&h[a2], 0x1000000u + (unsigned)fmaf(w.z, WSCALE, 0.5f));
    if (a3 < (unsigned)BINS) atomicAdd(&h[a3], 0x1000000u + (unsigned)fmaf(w.w, WSCALE, 0.5f));
  }
  __syncthreads();
  size_t base = (size_t)b * BINS;
  for (int i = threadIdx.x; i < BINS; i += 256) pu[base + i] = h[i];
}

// ---------------------------------------------------------------- pass B: reduce partials -> cnt, dinv
__global__ __launch_bounds__(256) void k_hreduce(const unsigned* __restrict__ pu,
                                                 int* __restrict__ cnt,
                                                 float* __restrict__ dinv) {
  int i = blockIdx.x * 256 + threadIdx.x;
  if (i >= T * N) return;
  int t = i / N, n = i - t * N;
  int r = n / BINS, rel = n - r * BINS;
  unsigned c = 0;
  unsigned wsum = 0;
  #pragma unroll
  for (int s = 0; s < SEG; ++s) {
    unsigned v = pu[((size_t)((t * NR + r) * SEG + s)) * BINS + rel];
    c += v >> 24;
    wsum += v & 0xFFFFFFu;
  }
  cnt[i] = (int)c;
  dinv[i] = rsqrtf(1.0f + (float)wsum * WINV);  // deg = 1 (self) + sum(ew)
}

// per-t exclusive scan of cnt -> rowptr (one block per t, 4 elems/thread)
__global__ __launch_bounds__(256) void k_scan(const int* __restrict__ cnt,
                                              int* __restrict__ rowptr) {
  int t = blockIdx.x;
  int lane = threadIdx.x & 63, wid = threadIdx.x >> 6;
  __shared__ int wsum[4];
  __shared__ int carry_s;
  if (threadIdx.x == 0) carry_s = 0;
  __syncthreads();
  const int4* cp = (const int4*)(cnt + (size_t)t * N);
  int4* rp = (int4*)(rowptr + (size_t)t * N);
  constexpr int NI4 = N / 4;  // 12500
  for (int base = 0; base < NI4; base += 256) {
    int i = base + threadIdx.x;
    int4 v = make_int4(0, 0, 0, 0);
    if (i < NI4) v = cp[i];
    int tot = v.x + v.y + v.z + v.w;
    int s = tot;
    #pragma unroll
    for (int off = 1; off < 64; off <<= 1) {
      int u = __shfl_up(s, off, 64);
      if (lane >= off) s += u;
    }
    if (lane == 63) wsum[wid] = s;
    int carry = carry_s;
    __syncthreads();
    int wadd = 0;
    #pragma unroll
    for (int w = 0; w < 4; ++w) if (w < wid) wadd += wsum[w];
    if (i < NI4) {
      int excl = carry + wadd + s - tot;
      int4 o;
      o.x = excl;
      o.y = excl + v.x;
      o.z = o.y + v.y;
      o.w = o.z + v.z;
      rp[i] = o;
    }
    __syncthreads();
    if (threadIdx.x == 0) carry_s = carry + wsum[0] + wsum[1] + wsum[2] + wsum[3];
    __syncthreads();
  }
}

// ---------------------------------------------------------------- pass C: partial counts -> absolute seg cursors (in place)
__global__ __launch_bounds__(256) void k_segoff(unsigned* __restrict__ pu,
                                                const int* __restrict__ rowptr) {
  int i = blockIdx.x * 256 + threadIdx.x;
  if (i >= T * N) return;
  int t = i / N, n = i - t * N;
  int r = n / BINS, rel = n - r * BINS;
  unsigned run = (unsigned)rowptr[i];
  #pragma unroll
  for (int s = 0; s < SEG; ++s) {
    size_t base = ((size_t)((t * NR + r) * SEG + s)) * BINS + rel;
    unsigned v = pu[base];
    pu[base] = run;
    run += v >> 24;
  }
}

// ---------------------------------------------------------------- pass D: place packed (src, raw ew) via LDS cursors
__global__ __launch_bounds__(256) void k_fill2(const int* __restrict__ ei,
                                               const float* __restrict__ ew,
                                               const unsigned* __restrict__ pu,
                                               int2* __restrict__ pk) {
  __shared__ int cur[BINS];
  int b = blockIdx.x;
  int s = b % SEG;
  int tr = b / SEG;
  int r = tr % NR;
  int t = tr / NR;
  size_t pbase = (size_t)b * BINS;
  for (int i = threadIdx.x; i < BINS; i += 256) cur[i] = (int)pu[pbase + i];
  __syncthreads();
  int bin0 = r * BINS;
  const int4* src4 = (const int4*)(ei + (size_t)t * 2 * E + s * ESEG);
  const int4* dst4 = (const int4*)(ei + (size_t)t * 2 * E + E + s * ESEG);
  const float4* ew4 = (const float4*)(ew + (size_t)t * E + s * ESEG);
  int2* pkt = pk + (size_t)t * E;
  for (int i = threadIdx.x; i < EV4; i += 256) {
    int4 d = dst4[i];
    int4 sv = src4[i];
    float4 w = ew4[i];
    unsigned a0 = (unsigned)(d.x - bin0);
    unsigned a1 = (unsigned)(d.y - bin0);
    unsigned a2 = (unsigned)(d.z - bin0);
    unsigned a3 = (unsigned)(d.w - bin0);
    if (a0 < (unsigned)BINS) {
      int pos = atomicAdd(&cur[a0], 1);
      pkt[pos] = make_int2(sv.x, __float_as_int(w.x));
    }
    if (a1 < (unsigned)BINS) {
      int pos = atomicAdd(&cur[a1], 1);
      pkt[pos] = make_int2(sv.y, __float_as_int(w.y));
    }
    if (a2 < (unsigned)BINS) {
      int pos = atomicAdd(&cur[a2], 1);
      pkt[pos] = make_int2(sv.z, __float_as_int(w.z));
    }
    if (a3 < (unsigned)BINS) {
      int pos = atomicAdd(&cur[a3], 1);
      pkt[pos] = make_int2(sv.w, __float_as_int(w.w));
    }
  }
}

// ---------------------------------------------------------------- weight prep: fp32 -> fp16 into one buffer
__global__ __launch_bounds__(256) void k_prep(const float* __restrict__ g1w,
                                              const float* __restrict__ g2w,
                                              const float* __restrict__ inw,
                                              const float* __restrict__ outw,
                                              const float* __restrict__ fcw,
                                              h16* __restrict__ Wb) {
  int i = blockIdx.x * 256 + threadIdx.x;
  if (i >= 32768) return;
  const float* src;
  int off;
  if (i < 8192)       { src = g1w;  off = 0; }
  else if (i < 12288) { src = g2w;  off = 8192; }
  else if (i < 24576) { src = inw;  off = 12288; }
  else if (i < 28672) { src = outw; off = 24576; }
  else                { src = fcw;  off = 28672; }
  Wb[i] = (h16)src[i - off];
}

// ---------------------------------------------------------------- MFMA GEMM: out[m][j] = sum_k W[j][k] * B[m][k]
// C/D layout (16x16x32): col = lane&15 -> m; row = quad*4+reg -> j.
// MODE 0: plain f16 out.  MODE 1: +bias, split q9/kv.  MODE 2: row-scale by biasp[m] (dinv).
template <int K, int NT, bool F16B, int MODE>
__global__ __launch_bounds__(256) void k_mm(const h16* __restrict__ Wb,
                                            const void* __restrict__ Bv,
                                            const float* __restrict__ biasp,
                                            h16* __restrict__ out,
                                            h16* __restrict__ q9,
                                            int Mwaves) {
  int wv = threadIdx.x >> 6, lane = threadIdx.x & 63;
  int wave = blockIdx.x * 4 + wv;
  if (wave >= Mwaves) return;
  int m0 = wave * 16;
  int half = lane & 15, quad = lane >> 4;
  constexpr int KS = K / 32;
  int m = m0 + half;
  float ds = 1.0f;
  if (MODE == 2) ds = biasp[m];
  f16x8 bfrag[KS];
  if (F16B) {
    const h16* Bp = (const h16*)Bv + (size_t)m * K + quad * 8;
    #pragma unroll
    for (int ks = 0; ks < KS; ++ks) bfrag[ks] = *(const f16x8*)(Bp + ks * 32);
  } else {
    const float* Bp = (const float*)Bv + (size_t)m * K + quad * 8;
    #pragma unroll
    for (int ks = 0; ks < KS; ++ks) {
      float4 f0 = *(const float4*)(Bp + ks * 32);
      float4 f1 = *(const float4*)(Bp + ks * 32 + 4);
      f16x8 b;
      b[0] = (h16)f0.x; b[1] = (h16)f0.y; b[2] = (h16)f0.z; b[3] = (h16)f0.w;
      b[4] = (h16)f1.x; b[5] = (h16)f1.y; b[6] = (h16)f1.z; b[7] = (h16)f1.w;
      bfrag[ks] = b;
    }
  }
  #pragma unroll
  for (int jt = 0; jt < NT; ++jt) {
    f32x4 acc = {0.f, 0.f, 0.f, 0.f};
    const h16* Wp = Wb + (size_t)(jt * 16 + half) * K + quad * 8;
    #pragma unroll
    for (int ks = 0; ks < KS; ++ks) {
      f16x8 afrag = *(const f16x8*)(Wp + ks * 32);
      acc = __builtin_amdgcn_mfma_f32_16x16x32_f16(afrag, bfrag[ks], acc, 0, 0, 0);
    }
    int j = jt * 16 + quad * 4;
    if (MODE == 1) {
      float4 b4 = *(const float4*)(biasp + j);
      acc[0] += b4.x; acc[1] += b4.y; acc[2] += b4.z; acc[3] += b4.w;
    }
    if (MODE == 2) {
      acc[0] *= ds; acc[1] *= ds; acc[2] *= ds; acc[3] *= ds;
    }
    f16x4 o;
    o[0] = (h16)acc[0]; o[1] = (h16)acc[1]; o[2] = (h16)acc[2]; o[3] = (h16)acc[3];
    if (MODE != 1) {
      *(f16x4*)(out + (size_t)m * (NT * 16) + j) = o;
    } else {
      if (jt < 4) {
        if (m % 10 == 9) *(f16x4*)(q9 + (size_t)(m / 10) * 64 + j) = o;
      } else {
        *(f16x4*)(out + (size_t)m * 128 + (j - 64)) = o;
      }
    }
  }
}

// ---------------------------------------------------------------- GCN aggregation (gather over CSR)
// 8 groups x 8 lanes; each lane covers 8 features (16B f16 loads). Edge records
// broadcast via same-address group loads. Group-reduce via wave-synchronous LDS.
// hw rows pre-scaled by dinv[src]; out = dn*(acc + hw'[n]) + b, relu.
template <bool SCATTER>
__global__ __launch_bounds__(256) void k_gather(
    const h16* __restrict__ hw, const int2* __restrict__ pk,
    const float* __restrict__ dinv, const int* __restrict__ rowptr,
    const int* __restrict__ cnt, const float* __restrict__ bias,
    const int* __restrict__ gidx, h16* __restrict__ outp) {
  __shared__ float red[4][8][64];  // [wave][group][feat] = 8 KB
  int wv = threadIdx.x >> 6, lane = threadIdx.x & 63;
  int t = blockIdx.y;
  int n = blockIdx.x * 4 + wv;
  const h16* hwt = hw + (size_t)t * N * D;
  const int2* pkt = pk + (size_t)t * E;
  float dn = dinv[t * N + n];
  int start = rowptr[t * N + n];
  int m = cnt[t * N + n];
  int grp = lane >> 3, sub = lane & 7;
  f32x4 accL = {0.f, 0.f, 0.f, 0.f};
  f32x4 accH = {0.f, 0.f, 0.f, 0.f};
  for (int e = grp; e < m; e += 8) {
    int2 rec = pkt[start + e];  // uniform within group -> broadcast
    float w = __int_as_float(rec.y);
    f16x8 h = *(const f16x8*)(hwt + (size_t)rec.x * D + sub * 8);
    #pragma unroll
    for (int j = 0; j < 4; ++j) accL[j] = fmaf(w, (float)h[j], accL[j]);
    #pragma unroll
    for (int j = 0; j < 4; ++j) accH[j] = fmaf(w, (float)h[j + 4], accH[j]);
  }
  // wave-synchronous LDS reduce across 8 groups
  float* rw = &red[wv][grp][sub * 8];
  *(f32x4*)(rw) = accL;
  *(f32x4*)(rw + 4) = accH;
  __builtin_amdgcn_wave_barrier();
  const float* rr = &red[wv][0][lane];
  float s = 0.f;
  #pragma unroll
  for (int g = 0; g < 8; ++g) s += rr[g * 64];
  // epilogue: lane owns feature `lane`
  float selfv = (float)hwt[(size_t)n * D + lane];
  float v = fmaxf(fmaf(dn, s + selfv, bias[lane]), 0.f);
  size_t ro;
  if (SCATTER) {
    int rr2 = gidx[(size_t)t * R + n];
    ro = ((size_t)rr2 * T + t) * D + lane;
  } else {
    ro = ((size_t)t * N + n) * D + lane;
  }
  outp[ro] = (h16)v;
}

// ---------------------------------------------------------------- attention core: one wave per r
__global__ __launch_bounds__(256) void k_attn2(const h16* __restrict__ kv,
                                               const h16* __restrict__ q9,
                                               h16* __restrict__ ao) {
  int wv = threadIdx.x >> 6, lane = threadIdx.x & 63;
  int r = blockIdx.x * 4 + wv;
  if (r >= R) return;
  float qv = (float)q9[(size_t)r * 64 + lane];
  const h16* kvr = kv + (size_t)r * T * 128;
  float sc[T], vv[T];
  #pragma unroll
  for (int s = 0; s < T; ++s) {
    float kk = (float)kvr[s * 128 + lane];
    vv[s] = (float)kvr[s * 128 + 64 + lane];
    float p = qv * kk;
    p += __shfl_xor(p, 8, 16);
    p += __shfl_xor(p, 4, 16);
    p += __shfl_xor(p, 2, 16);
    p += __shfl_xor(p, 1, 16);
    sc[s] = p * 0.25f;  // 1/sqrt(16)
  }
  float mx = sc[0];
  #pragma unroll
  for (int s = 1; s < T; ++s) mx = fmaxf(mx, sc[s]);
  float ssum = 0.f;
  #pragma unroll
  for (int s = 0; s < T; ++s) { sc[s] = expf(sc[s] - mx); ssum += sc[s]; }
  float rinv = 1.0f / ssum;
  float aov = 0.f;
  #pragma unroll
  for (int s = 0; s < T; ++s) aov = fmaf(sc[s] * rinv, vv[s], aov);
  ao[(size_t)r * 64 + lane] = (h16)aov;
}

// ---------------------------------------------------------------- LN1
__global__ __launch_bounds__(256) void k_ln1(const h16* __restrict__ te,
                                             const h16* __restrict__ proj,
                                             const float* __restrict__ outB,
                                             const float* __restrict__ w1,
                                             const float* __restrict__ w2,
                                             const float* __restrict__ g1,
                                             const float* __restrict__ b1,
                                             float* __restrict__ finf,
                                             h16* __restrict__ finb) {
  int wv = threadIdx.x >> 6, lane = threadIdx.x & 63;
  int r = blockIdx.x * 4 + wv;
  if (r >= R) return;
  float t9 = (float)te[((size_t)r * T + (T - 1)) * 64 + lane];
  float pr = (float)proj[(size_t)r * 64 + lane] + outB[lane];
  float pre = w1[(T - 1) * 64 + lane] * t9 + w2[(T - 1) * 64 + lane] * pr;
  float s1 = pre;
  #pragma unroll
  for (int off = 32; off >= 1; off >>= 1) s1 += __shfl_xor(s1, off, 64);
  float mu = s1 * (1.0f / 64.0f);
  float dv = pre - mu;
  float s2 = dv * dv;
  #pragma unroll
  for (int off = 32; off >= 1; off >>= 1) s2 += __shfl_xor(s2, off, 64);
  float rstd = 1.0f / sqrtf(s2 * (1.0f / 64.0f) + 1e-5f);
  float fin = dv * rstd * g1[lane] + b1[lane];
  finf[(size_t)r * 64 + lane] = fin;
  finb[(size_t)r * 64 + lane] = (h16)fin;
}

// ---------------------------------------------------------------- LN2
__global__ __launch_bounds__(256) void k_ln2(const float* __restrict__ finf,
                                             const h16* __restrict__ o2,
                                             const float* __restrict__ fcB,
                                             const float* __restrict__ w3,
                                             const float* __restrict__ w4,
                                             const float* __restrict__ g2,
                                             const float* __restrict__ b2,
                                             float* __restrict__ out) {
  int wv = threadIdx.x >> 6, lane = threadIdx.x & 63;
  int r = blockIdx.x * 4 + wv;
  if (r >= R) return;
  float fin = finf[(size_t)r * 64 + lane];
  float oo = (float)o2[(size_t)r * 64 + lane] + fcB[lane];
  float pre = w3[lane] * fin + w4[lane] * oo;
  float s1 = pre;
  #pragma unroll
  for (int off = 32; off >= 1; off >>= 1) s1 += __shfl_xor(s1, off, 64);
  float mu = s1 * (1.0f / 64.0f);
  float dv = pre - mu;
  float s2 = dv * dv;
  #pragma unroll
  for (int off = 32; off >= 1; off >>= 1) s2 += __shfl_xor(s2, off, 64);
  float rstd = 1.0f / sqrtf(s2 * (1.0f / 64.0f) + 1e-5f);
  out[(size_t)r * 64 + lane] = dv * rstd * g2[lane] + b2[lane];
}

}  // namespace

extern "C" void kernel_launch(void* const* d_in, const int* in_sizes, int n_in,
                              void* d_out, int out_size, void* d_ws, size_t ws_size,
                              hipStream_t stream) {
  const float* x      = (const float*)d_in[0];
  const int*   ei     = (const int*)d_in[1];
  const float* ew     = (const float*)d_in[2];
  const int*   gidx   = (const int*)d_in[3];
  const float* gcn1_w = (const float*)d_in[4];
  const float* gcn1_b = (const float*)d_in[5];
  const float* gcn2_w = (const float*)d_in[6];
  const float* gcn2_b = (const float*)d_in[7];
  const float* in_w   = (const float*)d_in[8];
  const float* in_b   = (const float*)d_in[9];
  const float* out_w  = (const float*)d_in[10];
  const float* out_b  = (const float*)d_in[11];
  const float* w1     = (const float*)d_in[12];
  const float* w2     = (const float*)d_in[13];
  const float* w3     = (const float*)d_in[14];
  const float* w4     = (const float*)d_in[15];
  const float* ln1_g  = (const float*)d_in[16];
  const float* ln1_b  = (const float*)d_in[17];
  const float* ln2_g  = (const float*)d_in[18];
  const float* ln2_b  = (const float*)d_in[19];
  const float* fc_w   = (const float*)d_in[20];
  const float* fc_b   = (const float*)d_in[21];
  float* outp = (float*)d_out;

  char* ws = (char*)d_ws;
  size_t off = 0;
  auto alloc = [&](size_t bytes) {
    void* p = ws + off;
    off += (bytes + 255) & ~(size_t)255;
    return p;
  };
  // persistent-tail region
  h16* h1te = (h16*)alloc(sizeof(h16) * (size_t)T * N * D);  // h1 / time_embeds
  h16* q9b  = (h16*)alloc(sizeof(h16) * (size_t)R * D);
  h16* aob  = (h16*)alloc(sizeof(h16) * (size_t)R * D);
  h16* proj = (h16*)alloc(sizeof(h16) * (size_t)R * D);
  float* finf = (float*)alloc(sizeof(float) * (size_t)R * D);
  h16* finb = (h16*)alloc(sizeof(h16) * (size_t)R * D);
  h16* o2b  = (h16*)alloc(sizeof(h16) * (size_t)R * D);
  h16* Wb   = (h16*)alloc(sizeof(h16) * 32768);
  // union region: graph-prep (dead after fill2/gather2) aliased with kv (live after)
  size_t u_base = off;
  float* dinv   = (float*)alloc(sizeof(float) * T * N);
  int*   cnt    = (int*)alloc(sizeof(int) * T * N);
  int*   rowptr = (int*)alloc(sizeof(int) * T * N);
  int2*  pk     = (int2*)alloc(sizeof(int2) * (size_t)T * E);
  size_t pu_off = off;
  unsigned* pu  = (unsigned*)alloc(sizeof(unsigned) * (size_t)T * NR * SEG * BINS);  // 36.7 MB
  // hw aliases pu (pu dead after k_fill2; hw first written at GCN1 k_mm) and extends beyond
  h16* hw = (h16*)(ws + pu_off);
  size_t hw_end = pu_off + sizeof(h16) * (size_t)T * N * D;
  if (hw_end > off) off = hw_end;
  // kv aliases the whole union region (everything above dead after gather2)
  h16* kv = (h16*)(ws + u_base);  // [T*N][128] f16 = 128 MB
  size_t kv_end = u_base + sizeof(h16) * (size_t)T * N * 128;
  if (kv_end > off) off = kv_end;

  const h16* W1b = Wb;           // gcn1_w  [64][128]
  const h16* W2b = Wb + 8192;    // gcn2_w  [64][64]
  const h16* WIb = Wb + 12288;   // in_w    [192][64]
  const h16* WOb = Wb + 24576;   // out_w   [64][64]
  const h16* WFb = Wb + 28672;   // fc_w    [64][64]

  const int M = T * N;
  const int MW = M / 16;   // 31250
  const int RW = R / 16;   // 3125
  const int PREP_BLOCKS = T * NR * SEG;  // 1120

  // graph prep — no global atomics
  k_hist<<<PREP_BLOCKS, 256, 0, stream>>>(ei, ew, pu);
  k_hreduce<<<(T * N + 255) / 256, 256, 0, stream>>>(pu, cnt, dinv);
  k_scan<<<T, 256, 0, stream>>>(cnt, rowptr);
  k_segoff<<<(T * N + 255) / 256, 256, 0, stream>>>(pu, rowptr);
  k_fill2<<<PREP_BLOCKS, 256, 0, stream>>>(ei, ew, pu, pk);
  k_prep<<<128, 256, 0, stream>>>(gcn1_w, gcn2_w, in_w, out_w, fc_w, Wb);

  // GCN stage (hw rows pre-scaled by dinv via MODE 2)
  dim3 gg(N / 4, T);
  k_mm<DIN, 4, false, 2><<<(MW + 3) / 4, 256, 0, stream>>>(W1b, x, dinv, hw, nullptr, MW);
  k_gather<false><<<gg, 256, 0, stream>>>(hw, pk, dinv, rowptr, cnt, gcn1_b, nullptr, h1te);
  k_mm<D, 4, true, 2><<<(MW + 3) / 4, 256, 0, stream>>>(W2b, h1te, dinv, hw, nullptr, MW);
  k_gather<true><<<gg, 256, 0, stream>>>(hw, pk, dinv, rowptr, cnt, gcn2_b, gidx, h1te);

  // attention tail
  k_mm<D, 12, true, 1><<<(MW + 3) / 4, 256, 0, stream>>>(WIb, h1te, in_b, kv, q9b, MW);
  k_attn2<<<(R + 3) / 4, 256, 0, stream>>>(kv, q9b, aob);
  k_mm<D, 4, true, 0><<<(RW + 3) / 4, 256, 0, stream>>>(WOb, aob, nullptr, proj, nullptr, RW);
  k_ln1<<<(R + 3) / 4, 256, 0, stream>>>(h1te, proj, out_b, w1, w2, ln1_g, ln1_b, finf, finb);
  k_mm<D, 4, true, 0><<<(RW + 3) / 4, 256, 0, stream>>>(WFb, finb, nullptr, o2b, nullptr, RW);
  k_ln2<<<(R + 3) / 4, 256, 0, stream>>>(finf, o2b, fc_b, w3, w4, ln2_g, ln2_b, outp);
}

// Round 3
// 1077.319 us; speedup vs baseline: 1.4884x; 1.1083x over previous
//
#include <hip/hip_runtime.h>
#include <cstdint>
#include <cstddef>

namespace {

constexpr int T = 10;
constexpr int N = 50000;
constexpr int R = 50000;
constexpr int DIN = 128;
constexpr int D = 64;
constexpr int E = 400000;

// LDS-binned edge-prep geometry
constexpr int BINS = 16384;             // bins per range (64 KB packed LDS)
constexpr int NR = 4;                   // ranges: 4*16384 = 65536 >= N
constexpr int SEG = 16;                 // edge segments per t (640 blocks total)
constexpr int ESEG = E / SEG;           // 25000 edges per segment
constexpr int EV4 = ESEG / 4;           // 6250 int4 groups per segment

// hist packing: count in bits [24..31], weight-sum fixed-point 2^-18 in bits [0..23]
constexpr float WSCALE = 262144.0f;     // 2^18
constexpr float WINV = 1.0f / 262144.0f;

typedef _Float16 h16;
typedef __attribute__((ext_vector_type(8))) _Float16 f16x8;
typedef __attribute__((ext_vector_type(4))) _Float16 f16x4;
typedef __attribute__((ext_vector_type(4))) float f32x4;

// ---------------------------------------------------------------- pass A: LDS histogram (packed u32)
__global__ __launch_bounds__(256) void k_hist(const int* __restrict__ ei,
                                              const float* __restrict__ ew,
                                              unsigned* __restrict__ pu) {
  __shared__ unsigned h[BINS];  // 64 KB
  int b = blockIdx.x;
  int s = b % SEG;
  int tr = b / SEG;
  int r = tr % NR;
  int t = tr / NR;
  for (int i = threadIdx.x; i < BINS; i += 256) h[i] = 0u;
  __syncthreads();
  int bin0 = r * BINS;
  const int4* dst4 = (const int4*)(ei + (size_t)t * 2 * E + E + s * ESEG);
  const float4* ew4 = (const float4*)(ew + (size_t)t * E + s * ESEG);
  for (int i = threadIdx.x; i < EV4; i += 256) {
    int4 d = dst4[i];
    float4 w = ew4[i];
    unsigned a0 = (unsigned)(d.x - bin0);
    unsigned a1 = (unsigned)(d.y - bin0);
    unsigned a2 = (unsigned)(d.z - bin0);
    unsigned a3 = (unsigned)(d.w - bin0);
    if (a0 < (unsigned)BINS) atomicAdd(&h[a0], 0x1000000u + (unsigned)fmaf(w.x, WSCALE, 0.5f));
    if (a1 < (unsigned)BINS) atomicAdd(&h[a1], 0x1000000u + (unsigned)fmaf(w.y, WSCALE, 0.5f));
    if (a2 < (unsigned)BINS) atomicAdd(&h[a2], 0x1000000u + (unsigned)fmaf(w.z, WSCALE, 0.5f));
    if (a3 < (unsigned)BINS) atomicAdd(&h[a3], 0x1000000u + (unsigned)fmaf(w.w, WSCALE, 0.5f));
  }
  __syncthreads();
  size_t base = (size_t)b * BINS;
  for (int i = threadIdx.x; i < BINS; i += 256) pu[base + i] = h[i];
}

// ---------------------------------------------------------------- pass B: reduce partials -> cnt, dinv
__global__ __launch_bounds__(256) void k_hreduce(const unsigned* __restrict__ pu,
                                                 int* __restrict__ cnt,
                                                 float* __restrict__ dinv) {
  int i = blockIdx.x * 256 + threadIdx.x;
  if (i >= T * N) return;
  int t = i / N, n = i - t * N;
  int r = n / BINS, rel = n - r * BINS;
  unsigned c = 0;
  unsigned wsum = 0;
  #pragma unroll
  for (int s = 0; s < SEG; ++s) {
    unsigned v = pu[((size_t)((t * NR + r) * SEG + s)) * BINS + rel];
    c += v >> 24;
    wsum += v & 0xFFFFFFu;
  }
  cnt[i] = (int)c;
  dinv[i] = rsqrtf(1.0f + (float)wsum * WINV);  // deg = 1 (self) + sum(ew)
}

// per-t exclusive scan of cnt -> rowptr (one block per t, 4 elems/thread)
__global__ __launch_bounds__(256) void k_scan(const int* __restrict__ cnt,
                                              int* __restrict__ rowptr) {
  int t = blockIdx.x;
  int lane = threadIdx.x & 63, wid = threadIdx.x >> 6;
  __shared__ int wsum[4];
  __shared__ int carry_s;
  if (threadIdx.x == 0) carry_s = 0;
  __syncthreads();
  const int4* cp = (const int4*)(cnt + (size_t)t * N);
  int4* rp = (int4*)(rowptr + (size_t)t * N);
  constexpr int NI4 = N / 4;  // 12500
  for (int base = 0; base < NI4; base += 256) {
    int i = base + threadIdx.x;
    int4 v = make_int4(0, 0, 0, 0);
    if (i < NI4) v = cp[i];
    int tot = v.x + v.y + v.z + v.w;
    int s = tot;
    #pragma unroll
    for (int off = 1; off < 64; off <<= 1) {
      int u = __shfl_up(s, off, 64);
      if (lane >= off) s += u;
    }
    if (lane == 63) wsum[wid] = s;
    int carry = carry_s;
    __syncthreads();
    int wadd = 0;
    #pragma unroll
    for (int w = 0; w < 4; ++w) if (w < wid) wadd += wsum[w];
    if (i < NI4) {
      int excl = carry + wadd + s - tot;
      int4 o;
      o.x = excl;
      o.y = excl + v.x;
      o.z = o.y + v.y;
      o.w = o.z + v.z;
      rp[i] = o;
    }
    __syncthreads();
    if (threadIdx.x == 0) carry_s = carry + wsum[0] + wsum[1] + wsum[2] + wsum[3];
    __syncthreads();
  }
}

// ---------------------------------------------------------------- pass C: partial counts -> absolute seg cursors (in place)
__global__ __launch_bounds__(256) void k_segoff(unsigned* __restrict__ pu,
                                                const int* __restrict__ rowptr) {
  int i = blockIdx.x * 256 + threadIdx.x;
  if (i >= T * N) return;
  int t = i / N, n = i - t * N;
  int r = n / BINS, rel = n - r * BINS;
  unsigned run = (unsigned)rowptr[i];
  #pragma unroll
  for (int s = 0; s < SEG; ++s) {
    size_t base = ((size_t)((t * NR + r) * SEG + s)) * BINS + rel;
    unsigned v = pu[base];
    pu[base] = run;
    run += v >> 24;
  }
}

// ---------------------------------------------------------------- pass D: place packed (src, raw ew) via LDS cursors
__global__ __launch_bounds__(256) void k_fill2(const int* __restrict__ ei,
                                               const float* __restrict__ ew,
                                               const unsigned* __restrict__ pu,
                                               int2* __restrict__ pk) {
  __shared__ int cur[BINS];  // 64 KB
  int b = blockIdx.x;
  int s = b % SEG;
  int tr = b / SEG;
  int r = tr % NR;
  int t = tr / NR;
  size_t pbase = (size_t)b * BINS;
  for (int i = threadIdx.x; i < BINS; i += 256) cur[i] = (int)pu[pbase + i];
  __syncthreads();
  int bin0 = r * BINS;
  const int4* src4 = (const int4*)(ei + (size_t)t * 2 * E + s * ESEG);
  const int4* dst4 = (const int4*)(ei + (size_t)t * 2 * E + E + s * ESEG);
  const float4* ew4 = (const float4*)(ew + (size_t)t * E + s * ESEG);
  int2* pkt = pk + (size_t)t * E;
  for (int i = threadIdx.x; i < EV4; i += 256) {
    int4 d = dst4[i];
    int4 sv = src4[i];
    float4 w = ew4[i];
    unsigned a0 = (unsigned)(d.x - bin0);
    unsigned a1 = (unsigned)(d.y - bin0);
    unsigned a2 = (unsigned)(d.z - bin0);
    unsigned a3 = (unsigned)(d.w - bin0);
    if (a0 < (unsigned)BINS) {
      int pos = atomicAdd(&cur[a0], 1);
      pkt[pos] = make_int2(sv.x, __float_as_int(w.x));
    }
    if (a1 < (unsigned)BINS) {
      int pos = atomicAdd(&cur[a1], 1);
      pkt[pos] = make_int2(sv.y, __float_as_int(w.y));
    }
    if (a2 < (unsigned)BINS) {
      int pos = atomicAdd(&cur[a2], 1);
      pkt[pos] = make_int2(sv.z, __float_as_int(w.z));
    }
    if (a3 < (unsigned)BINS) {
      int pos = atomicAdd(&cur[a3], 1);
      pkt[pos] = make_int2(sv.w, __float_as_int(w.w));
    }
  }
}

// ---------------------------------------------------------------- weight prep: fp32 -> fp16 into one buffer
__global__ __launch_bounds__(256) void k_prep(const float* __restrict__ g1w,
                                              const float* __restrict__ g2w,
                                              const float* __restrict__ inw,
                                              const float* __restrict__ outw,
                                              const float* __restrict__ fcw,
                                              h16* __restrict__ Wb) {
  int i = blockIdx.x * 256 + threadIdx.x;
  if (i >= 32768) return;
  const float* src;
  int off;
  if (i < 8192)       { src = g1w;  off = 0; }
  else if (i < 12288) { src = g2w;  off = 8192; }
  else if (i < 24576) { src = inw;  off = 12288; }
  else if (i < 28672) { src = outw; off = 24576; }
  else                { src = fcw;  off = 28672; }
  Wb[i] = (h16)src[i - off];
}

// ---------------------------------------------------------------- MFMA GEMM: out[m][j] = sum_k W[j][k] * B[m][k]
// C/D layout (16x16x32): col = lane&15 -> m; row = quad*4+reg -> j.
// MODE 0: plain f16 out.  MODE 1: +bias, split q9/kv.  MODE 2: row-scale by biasp[m] (dinv).
template <int K, int NT, bool F16B, int MODE>
__global__ __launch_bounds__(256) void k_mm(const h16* __restrict__ Wb,
                                            const void* __restrict__ Bv,
                                            const float* __restrict__ biasp,
                                            h16* __restrict__ out,
                                            h16* __restrict__ q9,
                                            int Mwaves) {
  int wv = threadIdx.x >> 6, lane = threadIdx.x & 63;
  int wave = blockIdx.x * 4 + wv;
  if (wave >= Mwaves) return;
  int m0 = wave * 16;
  int half = lane & 15, quad = lane >> 4;
  constexpr int KS = K / 32;
  int m = m0 + half;
  float ds = 1.0f;
  if (MODE == 2) ds = biasp[m];
  f16x8 bfrag[KS];
  if (F16B) {
    const h16* Bp = (const h16*)Bv + (size_t)m * K + quad * 8;
    #pragma unroll
    for (int ks = 0; ks < KS; ++ks) bfrag[ks] = *(const f16x8*)(Bp + ks * 32);
  } else {
    const float* Bp = (const float*)Bv + (size_t)m * K + quad * 8;
    #pragma unroll
    for (int ks = 0; ks < KS; ++ks) {
      float4 f0 = *(const float4*)(Bp + ks * 32);
      float4 f1 = *(const float4*)(Bp + ks * 32 + 4);
      f16x8 b;
      b[0] = (h16)f0.x; b[1] = (h16)f0.y; b[2] = (h16)f0.z; b[3] = (h16)f0.w;
      b[4] = (h16)f1.x; b[5] = (h16)f1.y; b[6] = (h16)f1.z; b[7] = (h16)f1.w;
      bfrag[ks] = b;
    }
  }
  #pragma unroll
  for (int jt = 0; jt < NT; ++jt) {
    f32x4 acc = {0.f, 0.f, 0.f, 0.f};
    const h16* Wp = Wb + (size_t)(jt * 16 + half) * K + quad * 8;
    #pragma unroll
    for (int ks = 0; ks < KS; ++ks) {
      f16x8 afrag = *(const f16x8*)(Wp + ks * 32);
      acc = __builtin_amdgcn_mfma_f32_16x16x32_f16(afrag, bfrag[ks], acc, 0, 0, 0);
    }
    int j = jt * 16 + quad * 4;
    if (MODE == 1) {
      float4 b4 = *(const float4*)(biasp + j);
      acc[0] += b4.x; acc[1] += b4.y; acc[2] += b4.z; acc[3] += b4.w;
    }
    if (MODE == 2) {
      acc[0] *= ds; acc[1] *= ds; acc[2] *= ds; acc[3] *= ds;
    }
    f16x4 o;
    o[0] = (h16)acc[0]; o[1] = (h16)acc[1]; o[2] = (h16)acc[2]; o[3] = (h16)acc[3];
    if (MODE != 1) {
      *(f16x4*)(out + (size_t)m * (NT * 16) + j) = o;
    } else {
      if (jt < 4) {
        if (m % 10 == 9) *(f16x4*)(q9 + (size_t)(m / 10) * 64 + j) = o;
      } else {
        *(f16x4*)(out + (size_t)m * 128 + (j - 64)) = o;
      }
    }
  }
}

// ---------------------------------------------------------------- GCN aggregation (gather over CSR)
// 2 nodes per wave, 4 groups x 8 lanes per node; each lane covers 8 features
// (16B f16 loads). Pair-unrolled edge loop: 2 recs + up to 8 rows in flight per
// node. Group-reduce via padded wave-synchronous LDS. hw rows pre-scaled by
// dinv[src]; out = dn*(acc + hw'[n]) + b, relu.
template <bool SCATTER>
__global__ __launch_bounds__(256) void k_gather(
    const h16* __restrict__ hw, const int2* __restrict__ pk,
    const float* __restrict__ dinv, const int* __restrict__ rowptr,
    const int* __restrict__ cnt, const float* __restrict__ bias,
    const int* __restrict__ gidx, h16* __restrict__ outp) {
  __shared__ __align__(16) float red[4][8][68];  // [wave][nd*4+grp][feat pad+4]
  int wv = threadIdx.x >> 6, lane = threadIdx.x & 63;
  int t = blockIdx.y;
  int nd = lane >> 5;            // which of the 2 nodes
  int grp = (lane >> 3) & 3;     // 4 edge-groups per node
  int sub = lane & 7;            // 8 feature-lanes per group
  int n = blockIdx.x * 8 + wv * 2 + nd;
  const h16* hwt = hw + (size_t)t * N * D;
  const int2* pkt = pk + (size_t)t * E;
  int start = rowptr[t * N + n];
  int m = cnt[t * N + n];
  // hoist independent epilogue loads (lane = feature for node nA/nB)
  int nA = blockIdx.x * 8 + wv * 2;
  int nB = nA + 1;
  float selfA = (float)hwt[(size_t)nA * D + lane];
  float selfB = (float)hwt[(size_t)nB * D + lane];
  float dnA = dinv[t * N + nA];
  float dnB = dinv[t * N + nB];
  float bi = bias[lane];
  f32x4 accL = {0.f, 0.f, 0.f, 0.f};
  f32x4 accH = {0.f, 0.f, 0.f, 0.f};
  int e = grp;
  for (; e + 4 < m; e += 8) {
    int2 ra = pkt[start + e];
    int2 rb = pkt[start + e + 4];
    float wa = __int_as_float(ra.y);
    float wb = __int_as_float(rb.y);
    f16x8 ha = *(const f16x8*)(hwt + (size_t)ra.x * D + sub * 8);
    f16x8 hb = *(const f16x8*)(hwt + (size_t)rb.x * D + sub * 8);
    #pragma unroll
    for (int j = 0; j < 4; ++j) {
      accL[j] = fmaf(wa, (float)ha[j], accL[j]);
      accH[j] = fmaf(wa, (float)ha[j + 4], accH[j]);
    }
    #pragma unroll
    for (int j = 0; j < 4; ++j) {
      accL[j] = fmaf(wb, (float)hb[j], accL[j]);
      accH[j] = fmaf(wb, (float)hb[j + 4], accH[j]);
    }
  }
  if (e < m) {
    int2 ra = pkt[start + e];
    float wa = __int_as_float(ra.y);
    f16x8 ha = *(const f16x8*)(hwt + (size_t)ra.x * D + sub * 8);
    #pragma unroll
    for (int j = 0; j < 4; ++j) {
      accL[j] = fmaf(wa, (float)ha[j], accL[j]);
      accH[j] = fmaf(wa, (float)ha[j + 4], accH[j]);
    }
  }
  // wave-synchronous LDS reduce across the 4 groups of each node
  float* rw = &red[wv][nd * 4 + grp][sub * 8];
  *(f32x4*)(rw) = accL;
  *(f32x4*)(rw + 4) = accH;
  __builtin_amdgcn_wave_barrier();
  // epilogue: lane owns feature `lane`, loops over the 2 nodes
  #pragma unroll
  for (int d2 = 0; d2 < 2; ++d2) {
    int nn = nA + d2;
    float s = red[wv][d2 * 4 + 0][lane] + red[wv][d2 * 4 + 1][lane] +
              red[wv][d2 * 4 + 2][lane] + red[wv][d2 * 4 + 3][lane];
    float selfv = d2 ? selfB : selfA;
    float dn = d2 ? dnB : dnA;
    float v = fmaxf(fmaf(dn, s + selfv, bi), 0.f);
    size_t ro;
    if (SCATTER) {
      int rr2 = gidx[(size_t)t * R + nn];
      ro = ((size_t)rr2 * T + t) * D + lane;
    } else {
      ro = ((size_t)t * N + nn) * D + lane;
    }
    outp[ro] = (h16)v;
  }
}

// ---------------------------------------------------------------- attention core: one wave per r
__global__ __launch_bounds__(256) void k_attn2(const h16* __restrict__ kv,
                                               const h16* __restrict__ q9,
                                               h16* __restrict__ ao) {
  int wv = threadIdx.x >> 6, lane = threadIdx.x & 63;
  int r = blockIdx.x * 4 + wv;
  if (r >= R) return;
  float qv = (float)q9[(size_t)r * 64 + lane];
  const h16* kvr = kv + (size_t)r * T * 128;
  float sc[T], vv[T];
  #pragma unroll
  for (int s = 0; s < T; ++s) {
    float kk = (float)kvr[s * 128 + lane];
    vv[s] = (float)kvr[s * 128 + 64 + lane];
    float p = qv * kk;
    p += __shfl_xor(p, 8, 16);
    p += __shfl_xor(p, 4, 16);
    p += __shfl_xor(p, 2, 16);
    p += __shfl_xor(p, 1, 16);
    sc[s] = p * 0.25f;  // 1/sqrt(16)
  }
  float mx = sc[0];
  #pragma unroll
  for (int s = 1; s < T; ++s) mx = fmaxf(mx, sc[s]);
  float ssum = 0.f;
  #pragma unroll
  for (int s = 0; s < T; ++s) { sc[s] = expf(sc[s] - mx); ssum += sc[s]; }
  float rinv = 1.0f / ssum;
  float aov = 0.f;
  #pragma unroll
  for (int s = 0; s < T; ++s) aov = fmaf(sc[s] * rinv, vv[s], aov);
  ao[(size_t)r * 64 + lane] = (h16)aov;
}

// ---------------------------------------------------------------- LN1
__global__ __launch_bounds__(256) void k_ln1(const h16* __restrict__ te,
                                             const h16* __restrict__ proj,
                                             const float* __restrict__ outB,
                                             const float* __restrict__ w1,
                                             const float* __restrict__ w2,
                                             const float* __restrict__ g1,
                                             const float* __restrict__ b1,
                                             float* __restrict__ finf,
                                             h16* __restrict__ finb) {
  int wv = threadIdx.x >> 6, lane = threadIdx.x & 63;
  int r = blockIdx.x * 4 + wv;
  if (r >= R) return;
  float t9 = (float)te[((size_t)r * T + (T - 1)) * 64 + lane];
  float pr = (float)proj[(size_t)r * 64 + lane] + outB[lane];
  float pre = w1[(T - 1) * 64 + lane] * t9 + w2[(T - 1) * 64 + lane] * pr;
  float s1 = pre;
  #pragma unroll
  for (int off = 32; off >= 1; off >>= 1) s1 += __shfl_xor(s1, off, 64);
  float mu = s1 * (1.0f / 64.0f);
  float dv = pre - mu;
  float s2 = dv * dv;
  #pragma unroll
  for (int off = 32; off >= 1; off >>= 1) s2 += __shfl_xor(s2, off, 64);
  float rstd = 1.0f / sqrtf(s2 * (1.0f / 64.0f) + 1e-5f);
  float fin = dv * rstd * g1[lane] + b1[lane];
  finf[(size_t)r * 64 + lane] = fin;
  finb[(size_t)r * 64 + lane] = (h16)fin;
}

// ---------------------------------------------------------------- LN2
__global__ __launch_bounds__(256) void k_ln2(const float* __restrict__ finf,
                                             const h16* __restrict__ o2,
                                             const float* __restrict__ fcB,
                                             const float* __restrict__ w3,
                                             const float* __restrict__ w4,
                                             const float* __restrict__ g2,
                                             const float* __restrict__ b2,
                                             float* __restrict__ out) {
  int wv = threadIdx.x >> 6, lane = threadIdx.x & 63;
  int r = blockIdx.x * 4 + wv;
  if (r >= R) return;
  float fin = finf[(size_t)r * 64 + lane];
  float oo = (float)o2[(size_t)r * 64 + lane] + fcB[lane];
  float pre = w3[lane] * fin + w4[lane] * oo;
  float s1 = pre;
  #pragma unroll
  for (int off = 32; off >= 1; off >>= 1) s1 += __shfl_xor(s1, off, 64);
  float mu = s1 * (1.0f / 64.0f);
  float dv = pre - mu;
  float s2 = dv * dv;
  #pragma unroll
  for (int off = 32; off >= 1; off >>= 1) s2 += __shfl_xor(s2, off, 64);
  float rstd = 1.0f / sqrtf(s2 * (1.0f / 64.0f) + 1e-5f);
  out[(size_t)r * 64 + lane] = dv * rstd * g2[lane] + b2[lane];
}

}  // namespace

extern "C" void kernel_launch(void* const* d_in, const int* in_sizes, int n_in,
                              void* d_out, int out_size, void* d_ws, size_t ws_size,
                              hipStream_t stream) {
  const float* x      = (const float*)d_in[0];
  const int*   ei     = (const int*)d_in[1];
  const float* ew     = (const float*)d_in[2];
  const int*   gidx   = (const int*)d_in[3];
  const float* gcn1_w = (const float*)d_in[4];
  const float* gcn1_b = (const float*)d_in[5];
  const float* gcn2_w = (const float*)d_in[6];
  const float* gcn2_b = (const float*)d_in[7];
  const float* in_w   = (const float*)d_in[8];
  const float* in_b   = (const float*)d_in[9];
  const float* out_w  = (const float*)d_in[10];
  const float* out_b  = (const float*)d_in[11];
  const float* w1     = (const float*)d_in[12];
  const float* w2     = (const float*)d_in[13];
  const float* w3     = (const float*)d_in[14];
  const float* w4     = (const float*)d_in[15];
  const float* ln1_g  = (const float*)d_in[16];
  const float* ln1_b  = (const float*)d_in[17];
  const float* ln2_g  = (const float*)d_in[18];
  const float* ln2_b  = (const float*)d_in[19];
  const float* fc_w   = (const float*)d_in[20];
  const float* fc_b   = (const float*)d_in[21];
  float* outp = (float*)d_out;

  char* ws = (char*)d_ws;
  size_t off = 0;
  auto alloc = [&](size_t bytes) {
    void* p = ws + off;
    off += (bytes + 255) & ~(size_t)255;
    return p;
  };
  // persistent-tail region
  h16* h1te = (h16*)alloc(sizeof(h16) * (size_t)T * N * D);  // h1 / time_embeds
  h16* q9b  = (h16*)alloc(sizeof(h16) * (size_t)R * D);
  h16* aob  = (h16*)alloc(sizeof(h16) * (size_t)R * D);
  h16* proj = (h16*)alloc(sizeof(h16) * (size_t)R * D);
  float* finf = (float*)alloc(sizeof(float) * (size_t)R * D);
  h16* finb = (h16*)alloc(sizeof(h16) * (size_t)R * D);
  h16* o2b  = (h16*)alloc(sizeof(h16) * (size_t)R * D);
  h16* Wb   = (h16*)alloc(sizeof(h16) * 32768);
  // union region: graph-prep (dead after fill2/gather2) aliased with kv (live after)
  size_t u_base = off;
  float* dinv   = (float*)alloc(sizeof(float) * T * N);
  int*   cnt    = (int*)alloc(sizeof(int) * T * N);
  int*   rowptr = (int*)alloc(sizeof(int) * T * N);
  int2*  pk     = (int2*)alloc(sizeof(int2) * (size_t)T * E);
  size_t pu_off = off;
  unsigned* pu  = (unsigned*)alloc(sizeof(unsigned) * (size_t)T * NR * SEG * BINS);  // 41.9 MB
  // hw aliases pu (pu dead after k_fill2; hw first written at GCN1 k_mm) and extends beyond
  h16* hw = (h16*)(ws + pu_off);
  size_t hw_end = pu_off + sizeof(h16) * (size_t)T * N * D;
  if (hw_end > off) off = hw_end;
  // kv aliases the whole union region (everything above dead after gather2)
  h16* kv = (h16*)(ws + u_base);  // [T*N][128] f16 = 128 MB
  size_t kv_end = u_base + sizeof(h16) * (size_t)T * N * 128;
  if (kv_end > off) off = kv_end;

  const h16* W1b = Wb;           // gcn1_w  [64][128]
  const h16* W2b = Wb + 8192;    // gcn2_w  [64][64]
  const h16* WIb = Wb + 12288;   // in_w    [192][64]
  const h16* WOb = Wb + 24576;   // out_w   [64][64]
  const h16* WFb = Wb + 28672;   // fc_w    [64][64]

  const int M = T * N;
  const int MW = M / 16;   // 31250
  const int RW = R / 16;   // 3125
  const int PREP_BLOCKS = T * NR * SEG;  // 640

  // graph prep — no global atomics
  k_hist<<<PREP_BLOCKS, 256, 0, stream>>>(ei, ew, pu);
  k_hreduce<<<(T * N + 255) / 256, 256, 0, stream>>>(pu, cnt, dinv);
  k_scan<<<T, 256, 0, stream>>>(cnt, rowptr);
  k_segoff<<<(T * N + 255) / 256, 256, 0, stream>>>(pu, rowptr);
  k_fill2<<<PREP_BLOCKS, 256, 0, stream>>>(ei, ew, pu, pk);
  k_prep<<<128, 256, 0, stream>>>(gcn1_w, gcn2_w, in_w, out_w, fc_w, Wb);

  // GCN stage (hw rows pre-scaled by dinv via MODE 2)
  dim3 gg(N / 8, T);
  k_mm<DIN, 4, false, 2><<<(MW + 3) / 4, 256, 0, stream>>>(W1b, x, dinv, hw, nullptr, MW);
  k_gather<false><<<gg, 256, 0, stream>>>(hw, pk, dinv, rowptr, cnt, gcn1_b, nullptr, h1te);
  k_mm<D, 4, true, 2><<<(MW + 3) / 4, 256, 0, stream>>>(W2b, h1te, dinv, hw, nullptr, MW);
  k_gather<true><<<gg, 256, 0, stream>>>(hw, pk, dinv, rowptr, cnt, gcn2_b, gidx, h1te);

  // attention tail
  k_mm<D, 12, true, 1><<<(MW + 3) / 4, 256, 0, stream>>>(WIb, h1te, in_b, kv, q9b, MW);
  k_attn2<<<(R + 3) / 4, 256, 0, stream>>>(kv, q9b, aob);
  k_mm<D, 4, true, 0><<<(RW + 3) / 4, 256, 0, stream>>>(WOb, aob, nullptr, proj, nullptr, RW);
  k_ln1<<<(R + 3) / 4, 256, 0, stream>>>(h1te, proj, out_b, w1, w2, ln1_g, ln1_b, finf, finb);
  k_mm<D, 4, true, 0><<<(RW + 3) / 4, 256, 0, stream>>>(WFb, finb, nullptr, o2b, nullptr, RW);
  k_ln2<<<(R + 3) / 4, 256, 0, stream>>>(finf, o2b, fc_b, w3, w4, ln2_g, ln2_b, outp);
}

// Round 4
// 985.720 us; speedup vs baseline: 1.6267x; 1.0929x over previous
//
#include <hip/hip_runtime.h>
#include <cstdint>
#include <cstddef>

namespace {

constexpr int T = 10;
constexpr int N = 50000;
constexpr int R = 50000;
constexpr int DIN = 128;
constexpr int D = 64;
constexpr int E = 400000;

// LDS-binned edge-prep geometry
constexpr int BINS = 16384;             // bins per range (64 KB packed LDS)
constexpr int NR = 4;                   // ranges: 4*16384 = 65536 >= N
constexpr int SEG = 25;                 // edge segments per t (1000 blocks total)
constexpr int ESEG = E / SEG;           // 16000 edges per segment
constexpr int EV4 = ESEG / 4;           // 4000 int4 groups per segment

// hist packing: count in bits [24..31], weight-sum fixed-point 2^-18 in bits [0..23]
constexpr float WSCALE = 262144.0f;     // 2^18
constexpr float WINV = 1.0f / 262144.0f;

typedef _Float16 h16;
typedef __attribute__((ext_vector_type(8))) _Float16 f16x8;
typedef __attribute__((ext_vector_type(4))) _Float16 f16x4;
typedef __attribute__((ext_vector_type(4))) float f32x4;

// ---------------------------------------------------------------- pass A: LDS histogram (packed u32)
__global__ __launch_bounds__(256) void k_hist(const int* __restrict__ ei,
                                              const float* __restrict__ ew,
                                              unsigned* __restrict__ pu) {
  __shared__ unsigned h[BINS];  // 64 KB
  int b = blockIdx.x;
  int s = b % SEG;
  int tr = b / SEG;
  int r = tr % NR;
  int t = tr / NR;
  for (int i = threadIdx.x; i < BINS; i += 256) h[i] = 0u;
  __syncthreads();
  int bin0 = r * BINS;
  const int4* dst4 = (const int4*)(ei + (size_t)t * 2 * E + E + s * ESEG);
  const float4* ew4 = (const float4*)(ew + (size_t)t * E + s * ESEG);
  for (int i = threadIdx.x; i < EV4; i += 256) {
    int4 d = dst4[i];
    float4 w = ew4[i];
    unsigned a0 = (unsigned)(d.x - bin0);
    unsigned a1 = (unsigned)(d.y - bin0);
    unsigned a2 = (unsigned)(d.z - bin0);
    unsigned a3 = (unsigned)(d.w - bin0);
    if (a0 < (unsigned)BINS) atomicAdd(&h[a0], 0x1000000u + (unsigned)fmaf(w.x, WSCALE, 0.5f));
    if (a1 < (unsigned)BINS) atomicAdd(&h[a1], 0x1000000u + (unsigned)fmaf(w.y, WSCALE, 0.5f));
    if (a2 < (unsigned)BINS) atomicAdd(&h[a2], 0x1000000u + (unsigned)fmaf(w.z, WSCALE, 0.5f));
    if (a3 < (unsigned)BINS) atomicAdd(&h[a3], 0x1000000u + (unsigned)fmaf(w.w, WSCALE, 0.5f));
  }
  __syncthreads();
  size_t base = (size_t)b * BINS;
  for (int i = threadIdx.x; i < BINS; i += 256) pu[base + i] = h[i];
}

// ---------------------------------------------------------------- pass B: reduce partials -> cnt, dinv
__global__ __launch_bounds__(256) void k_hreduce(const unsigned* __restrict__ pu,
                                                 int* __restrict__ cnt,
                                                 float* __restrict__ dinv) {
  int i = blockIdx.x * 256 + threadIdx.x;
  if (i >= T * N) return;
  int t = i / N, n = i - t * N;
  int r = n / BINS, rel = n - r * BINS;
  unsigned c = 0;
  unsigned wsum = 0;
  #pragma unroll
  for (int s = 0; s < SEG; ++s) {
    unsigned v = pu[((size_t)((t * NR + r) * SEG + s)) * BINS + rel];
    c += v >> 24;
    wsum += v & 0xFFFFFFu;
  }
  cnt[i] = (int)c;
  dinv[i] = rsqrtf(1.0f + (float)wsum * WINV);  // deg = 1 (self) + sum(ew)
}

// per-t exclusive scan of cnt -> rowptr (one block per t, 4 elems/thread)
__global__ __launch_bounds__(256) void k_scan(const int* __restrict__ cnt,
                                              int* __restrict__ rowptr) {
  int t = blockIdx.x;
  int lane = threadIdx.x & 63, wid = threadIdx.x >> 6;
  __shared__ int wsum[4];
  __shared__ int carry_s;
  if (threadIdx.x == 0) carry_s = 0;
  __syncthreads();
  const int4* cp = (const int4*)(cnt + (size_t)t * N);
  int4* rp = (int4*)(rowptr + (size_t)t * N);
  constexpr int NI4 = N / 4;  // 12500
  for (int base = 0; base < NI4; base += 256) {
    int i = base + threadIdx.x;
    int4 v = make_int4(0, 0, 0, 0);
    if (i < NI4) v = cp[i];
    int tot = v.x + v.y + v.z + v.w;
    int s = tot;
    #pragma unroll
    for (int off = 1; off < 64; off <<= 1) {
      int u = __shfl_up(s, off, 64);
      if (lane >= off) s += u;
    }
    if (lane == 63) wsum[wid] = s;
    int carry = carry_s;
    __syncthreads();
    int wadd = 0;
    #pragma unroll
    for (int w = 0; w < 4; ++w) if (w < wid) wadd += wsum[w];
    if (i < NI4) {
      int excl = carry + wadd + s - tot;
      int4 o;
      o.x = excl;
      o.y = excl + v.x;
      o.z = o.y + v.y;
      o.w = o.z + v.z;
      rp[i] = o;
    }
    __syncthreads();
    if (threadIdx.x == 0) carry_s = carry + wsum[0] + wsum[1] + wsum[2] + wsum[3];
    __syncthreads();
  }
}

// ---------------------------------------------------------------- pass C: partial counts -> absolute seg cursors (in place)
__global__ __launch_bounds__(256) void k_segoff(unsigned* __restrict__ pu,
                                                const int* __restrict__ rowptr) {
  int i = blockIdx.x * 256 + threadIdx.x;
  if (i >= T * N) return;
  int t = i / N, n = i - t * N;
  int r = n / BINS, rel = n - r * BINS;
  unsigned run = (unsigned)rowptr[i];
  #pragma unroll
  for (int s = 0; s < SEG; ++s) {
    size_t base = ((size_t)((t * NR + r) * SEG + s)) * BINS + rel;
    unsigned v = pu[base];
    pu[base] = run;
    run += v >> 24;
  }
}

// ---------------------------------------------------------------- pass D: place packed (src, raw ew) via LDS cursors
__global__ __launch_bounds__(256) void k_fill2(const int* __restrict__ ei,
                                               const float* __restrict__ ew,
                                               const unsigned* __restrict__ pu,
                                               int2* __restrict__ pk) {
  __shared__ int cur[BINS];  // 64 KB
  int b = blockIdx.x;
  int s = b % SEG;
  int tr = b / SEG;
  int r = tr % NR;
  int t = tr / NR;
  size_t pbase = (size_t)b * BINS;
  for (int i = threadIdx.x; i < BINS; i += 256) cur[i] = (int)pu[pbase + i];
  __syncthreads();
  int bin0 = r * BINS;
  const int4* src4 = (const int4*)(ei + (size_t)t * 2 * E + s * ESEG);
  const int4* dst4 = (const int4*)(ei + (size_t)t * 2 * E + E + s * ESEG);
  const float4* ew4 = (const float4*)(ew + (size_t)t * E + s * ESEG);
  int2* pkt = pk + (size_t)t * E;
  for (int i = threadIdx.x; i < EV4; i += 256) {
    int4 d = dst4[i];
    int4 sv = src4[i];
    float4 w = ew4[i];
    unsigned a0 = (unsigned)(d.x - bin0);
    unsigned a1 = (unsigned)(d.y - bin0);
    unsigned a2 = (unsigned)(d.z - bin0);
    unsigned a3 = (unsigned)(d.w - bin0);
    if (a0 < (unsigned)BINS) {
      int pos = atomicAdd(&cur[a0], 1);
      pkt[pos] = make_int2(sv.x, __float_as_int(w.x));
    }
    if (a1 < (unsigned)BINS) {
      int pos = atomicAdd(&cur[a1], 1);
      pkt[pos] = make_int2(sv.y, __float_as_int(w.y));
    }
    if (a2 < (unsigned)BINS) {
      int pos = atomicAdd(&cur[a2], 1);
      pkt[pos] = make_int2(sv.z, __float_as_int(w.z));
    }
    if (a3 < (unsigned)BINS) {
      int pos = atomicAdd(&cur[a3], 1);
      pkt[pos] = make_int2(sv.w, __float_as_int(w.w));
    }
  }
}

// ---------------------------------------------------------------- weight prep: fp32 -> fp16 into one buffer
__global__ __launch_bounds__(256) void k_prep(const float* __restrict__ g1w,
                                              const float* __restrict__ g2w,
                                              const float* __restrict__ inw,
                                              const float* __restrict__ outw,
                                              const float* __restrict__ fcw,
                                              h16* __restrict__ Wb) {
  int i = blockIdx.x * 256 + threadIdx.x;
  if (i >= 32768) return;
  const float* src;
  int off;
  if (i < 8192)       { src = g1w;  off = 0; }
  else if (i < 12288) { src = g2w;  off = 8192; }
  else if (i < 24576) { src = inw;  off = 12288; }
  else if (i < 28672) { src = outw; off = 24576; }
  else                { src = fcw;  off = 28672; }
  Wb[i] = (h16)src[i - off];
}

// ---------------------------------------------------------------- MFMA GEMM: out[m][j] = sum_k W[j][k] * B[m][k]
// C/D layout (16x16x32): col = lane&15 -> m; row = quad*4+reg -> j.
// MODE 0: plain f16 out.  MODE 2: row-scale by biasp[m] (dinv).
template <int K, int NT, bool F16B, int MODE>
__global__ __launch_bounds__(256) void k_mm(const h16* __restrict__ Wb,
                                            const void* __restrict__ Bv,
                                            const float* __restrict__ biasp,
                                            h16* __restrict__ out,
                                            int Mwaves) {
  int wv = threadIdx.x >> 6, lane = threadIdx.x & 63;
  int wave = blockIdx.x * 4 + wv;
  if (wave >= Mwaves) return;
  int m0 = wave * 16;
  int half = lane & 15, quad = lane >> 4;
  constexpr int KS = K / 32;
  int m = m0 + half;
  float ds = 1.0f;
  if (MODE == 2) ds = biasp[m];
  f16x8 bfrag[KS];
  if (F16B) {
    const h16* Bp = (const h16*)Bv + (size_t)m * K + quad * 8;
    #pragma unroll
    for (int ks = 0; ks < KS; ++ks) bfrag[ks] = *(const f16x8*)(Bp + ks * 32);
  } else {
    const float* Bp = (const float*)Bv + (size_t)m * K + quad * 8;
    #pragma unroll
    for (int ks = 0; ks < KS; ++ks) {
      float4 f0 = *(const float4*)(Bp + ks * 32);
      float4 f1 = *(const float4*)(Bp + ks * 32 + 4);
      f16x8 b;
      b[0] = (h16)f0.x; b[1] = (h16)f0.y; b[2] = (h16)f0.z; b[3] = (h16)f0.w;
      b[4] = (h16)f1.x; b[5] = (h16)f1.y; b[6] = (h16)f1.z; b[7] = (h16)f1.w;
      bfrag[ks] = b;
    }
  }
  #pragma unroll
  for (int jt = 0; jt < NT; ++jt) {
    f32x4 acc = {0.f, 0.f, 0.f, 0.f};
    const h16* Wp = Wb + (size_t)(jt * 16 + half) * K + quad * 8;
    #pragma unroll
    for (int ks = 0; ks < KS; ++ks) {
      f16x8 afrag = *(const f16x8*)(Wp + ks * 32);
      acc = __builtin_amdgcn_mfma_f32_16x16x32_f16(afrag, bfrag[ks], acc, 0, 0, 0);
    }
    int j = jt * 16 + quad * 4;
    if (MODE == 2) {
      acc[0] *= ds; acc[1] *= ds; acc[2] *= ds; acc[3] *= ds;
    }
    f16x4 o;
    o[0] = (h16)acc[0]; o[1] = (h16)acc[1]; o[2] = (h16)acc[2]; o[3] = (h16)acc[3];
    *(f16x4*)(out + (size_t)m * (NT * 16) + j) = o;
  }
}

// ---------------------------------------------------------------- GCN aggregation (gather over CSR)
// 2 nodes per wave, 4 groups x 8 lanes per node; each lane covers 8 features
// (16B f16 loads). Pair-unrolled edge loop.
template <bool SCATTER>
__global__ __launch_bounds__(256) void k_gather(
    const h16* __restrict__ hw, const int2* __restrict__ pk,
    const float* __restrict__ dinv, const int* __restrict__ rowptr,
    const int* __restrict__ cnt, const float* __restrict__ bias,
    const int* __restrict__ gidx, h16* __restrict__ outp) {
  __shared__ __align__(16) float red[4][8][68];  // [wave][nd*4+grp][feat pad+4]
  int wv = threadIdx.x >> 6, lane = threadIdx.x & 63;
  int t = blockIdx.y;
  int nd = lane >> 5;            // which of the 2 nodes
  int grp = (lane >> 3) & 3;     // 4 edge-groups per node
  int sub = lane & 7;            // 8 feature-lanes per group
  int n = blockIdx.x * 8 + wv * 2 + nd;
  const h16* hwt = hw + (size_t)t * N * D;
  const int2* pkt = pk + (size_t)t * E;
  int start = rowptr[t * N + n];
  int m = cnt[t * N + n];
  // hoist independent epilogue loads (lane = feature for node nA/nB)
  int nA = blockIdx.x * 8 + wv * 2;
  int nB = nA + 1;
  float selfA = (float)hwt[(size_t)nA * D + lane];
  float selfB = (float)hwt[(size_t)nB * D + lane];
  float dnA = dinv[t * N + nA];
  float dnB = dinv[t * N + nB];
  float bi = bias[lane];
  f32x4 accL = {0.f, 0.f, 0.f, 0.f};
  f32x4 accH = {0.f, 0.f, 0.f, 0.f};
  int e = grp;
  for (; e + 4 < m; e += 8) {
    int2 ra = pkt[start + e];
    int2 rb = pkt[start + e + 4];
    float wa = __int_as_float(ra.y);
    float wb = __int_as_float(rb.y);
    f16x8 ha = *(const f16x8*)(hwt + (size_t)ra.x * D + sub * 8);
    f16x8 hb = *(const f16x8*)(hwt + (size_t)rb.x * D + sub * 8);
    #pragma unroll
    for (int j = 0; j < 4; ++j) {
      accL[j] = fmaf(wa, (float)ha[j], accL[j]);
      accH[j] = fmaf(wa, (float)ha[j + 4], accH[j]);
    }
    #pragma unroll
    for (int j = 0; j < 4; ++j) {
      accL[j] = fmaf(wb, (float)hb[j], accL[j]);
      accH[j] = fmaf(wb, (float)hb[j + 4], accH[j]);
    }
  }
  if (e < m) {
    int2 ra = pkt[start + e];
    float wa = __int_as_float(ra.y);
    f16x8 ha = *(const f16x8*)(hwt + (size_t)ra.x * D + sub * 8);
    #pragma unroll
    for (int j = 0; j < 4; ++j) {
      accL[j] = fmaf(wa, (float)ha[j], accL[j]);
      accH[j] = fmaf(wa, (float)ha[j + 4], accH[j]);
    }
  }
  // wave-synchronous LDS reduce across the 4 groups of each node
  float* rw = &red[wv][nd * 4 + grp][sub * 8];
  *(f32x4*)(rw) = accL;
  *(f32x4*)(rw + 4) = accH;
  __builtin_amdgcn_wave_barrier();
  // epilogue: lane owns feature `lane`, loops over the 2 nodes
  #pragma unroll
  for (int d2 = 0; d2 < 2; ++d2) {
    int nn = nA + d2;
    float s = red[wv][d2 * 4 + 0][lane] + red[wv][d2 * 4 + 1][lane] +
              red[wv][d2 * 4 + 2][lane] + red[wv][d2 * 4 + 3][lane];
    float selfv = d2 ? selfB : selfA;
    float dn = d2 ? dnB : dnA;
    float v = fmaxf(fmaf(dn, s + selfv, bi), 0.f);
    size_t ro;
    if (SCATTER) {
      int rr2 = gidx[(size_t)t * R + nn];
      ro = ((size_t)rr2 * T + t) * D + lane;
    } else {
      ro = ((size_t)t * N + nn) * D + lane;
    }
    outp[ro] = (h16)v;
  }
}

// ---------------------------------------------------------------- fused attention tail
// One block = 16 r's (160 te rows). qkv MFMA -> LDS, attention, out_proj MFMA,
// LN1, fc MFMA, LN2 -> global f32 out. kv never touches global memory.
constexpr int KVP = 132;   // kv row pad (f16) -> 264 B rows, 2-way bank spread
constexpr int P72 = 72;    // 16-row tile pad  -> 144 B rows, 16B-aligned

__global__ __launch_bounds__(256) void k_tail(
    const h16* __restrict__ te,      // [R*T][64] f16
    const h16* __restrict__ WIb,     // in_proj [192][64]
    const float* __restrict__ inB,
    const h16* __restrict__ WOb,     // out_proj [64][64]
    const float* __restrict__ outB,
    const h16* __restrict__ WFb,     // fc [64][64]
    const float* __restrict__ fcB,
    const float* __restrict__ w1,
    const float* __restrict__ w2,
    const float* __restrict__ w3,
    const float* __restrict__ w4,
    const float* __restrict__ g1, const float* __restrict__ b1,
    const float* __restrict__ g2, const float* __restrict__ b2,
    float* __restrict__ outp) {
  __shared__ __align__(16) h16 kvl[160][KVP];   // k cols 0..63, v cols 64..127
  __shared__ __align__(16) h16 ql[16][P72];
  __shared__ __align__(16) h16 aol[16][P72];
  __shared__ __align__(16) h16 tbuf[16][P72];   // proj, then o2
  __shared__ __align__(16) h16 fbuf[16][P72];   // finb
  __shared__ __align__(16) float pf[16][64];    // fin f32

  int wv = threadIdx.x >> 6, lane = threadIdx.x & 63;
  int half = lane & 15, quad = lane >> 4;
  int g0 = blockIdx.x * 160;  // first global te row (r0*T)

  // ---- step 1: qkv = te @ in_w^T (+b) into LDS
  for (int tt = wv; tt < 10; tt += 4) {
    int lr = tt * 16 + half;  // local row 0..159
    const h16* Bp = te + (size_t)(g0 + lr) * 64 + quad * 8;
    f16x8 b0 = *(const f16x8*)(Bp);
    f16x8 b1f = *(const f16x8*)(Bp + 32);
    int rloc = lr / 10;
    bool isq = (lr - rloc * 10) == 9;
    #pragma unroll
    for (int jt = 0; jt < 12; ++jt) {
      f32x4 acc = {0.f, 0.f, 0.f, 0.f};
      const h16* Wp = WIb + (size_t)(jt * 16 + half) * 64 + quad * 8;
      acc = __builtin_amdgcn_mfma_f32_16x16x32_f16(*(const f16x8*)(Wp), b0, acc, 0, 0, 0);
      acc = __builtin_amdgcn_mfma_f32_16x16x32_f16(*(const f16x8*)(Wp + 32), b1f, acc, 0, 0, 0);
      int j = jt * 16 + quad * 4;
      float4 b4 = *(const float4*)(inB + j);
      f16x4 o;
      o[0] = (h16)(acc[0] + b4.x); o[1] = (h16)(acc[1] + b4.y);
      o[2] = (h16)(acc[2] + b4.z); o[3] = (h16)(acc[3] + b4.w);
      if (jt < 4) {
        if (isq) *(f16x4*)(&ql[rloc][j]) = o;
      } else {
        *(f16x4*)(&kvl[lr][j - 64]) = o;
      }
    }
  }
  __syncthreads();

  // ---- step 2: attention (one wave per r, 4 rounds); lane = feature
  #pragma unroll
  for (int i = 0; i < 4; ++i) {
    int rl = wv * 4 + i;
    float qv = (float)ql[rl][lane];
    float sc[T], vv[T];
    #pragma unroll
    for (int s = 0; s < T; ++s) {
      float kk = (float)kvl[rl * 10 + s][lane];
      vv[s] = (float)kvl[rl * 10 + s][64 + lane];
      float p = qv * kk;
      p += __shfl_xor(p, 8, 16);
      p += __shfl_xor(p, 4, 16);
      p += __shfl_xor(p, 2, 16);
      p += __shfl_xor(p, 1, 16);
      sc[s] = p * 0.25f;  // 1/sqrt(16)
    }
    float mx = sc[0];
    #pragma unroll
    for (int s = 1; s < T; ++s) mx = fmaxf(mx, sc[s]);
    float ssum = 0.f;
    #pragma unroll
    for (int s = 0; s < T; ++s) { sc[s] = expf(sc[s] - mx); ssum += sc[s]; }
    float rinv = 1.0f / ssum;
    float aov = 0.f;
    #pragma unroll
    for (int s = 0; s < T; ++s) aov = fmaf(sc[s] * rinv, vv[s], aov);
    aol[rl][lane] = (h16)aov;
  }
  __syncthreads();

  // ---- step 3: proj = ao @ out_w^T + outB (one 16x64 tile; wave wv owns jt=wv)
  {
    const h16* Bp = &aol[half][quad * 8];
    f16x8 b0 = *(const f16x8*)(Bp);
    f16x8 b1f = *(const f16x8*)(Bp + 32);
    f32x4 acc = {0.f, 0.f, 0.f, 0.f};
    const h16* Wp = WOb + (size_t)(wv * 16 + half) * 64 + quad * 8;
    acc = __builtin_amdgcn_mfma_f32_16x16x32_f16(*(const f16x8*)(Wp), b0, acc, 0, 0, 0);
    acc = __builtin_amdgcn_mfma_f32_16x16x32_f16(*(const f16x8*)(Wp + 32), b1f, acc, 0, 0, 0);
    int j = wv * 16 + quad * 4;
    float4 b4 = *(const float4*)(outB + j);
    f16x4 o;
    o[0] = (h16)(acc[0] + b4.x); o[1] = (h16)(acc[1] + b4.y);
    o[2] = (h16)(acc[2] + b4.z); o[3] = (h16)(acc[3] + b4.w);
    *(f16x4*)(&tbuf[half][j]) = o;
  }
  __syncthreads();

  // ---- step 4: LN1 per r (one wave per r, 4 rounds)
  {
    float w1l = w1[(T - 1) * 64 + lane];
    float w2l = w2[(T - 1) * 64 + lane];
    float g1l = g1[lane], b1l = b1[lane];
    #pragma unroll
    for (int i = 0; i < 4; ++i) {
      int rl = wv * 4 + i;
      float t9 = (float)te[(size_t)(g0 + rl * 10 + 9) * 64 + lane];
      float pr = (float)tbuf[rl][lane];
      float pre = w1l * t9 + w2l * pr;
      float s1 = pre;
      #pragma unroll
      for (int off = 32; off >= 1; off >>= 1) s1 += __shfl_xor(s1, off, 64);
      float mu = s1 * (1.0f / 64.0f);
      float dv = pre - mu;
      float s2 = dv * dv;
      #pragma unroll
      for (int off = 32; off >= 1; off >>= 1) s2 += __shfl_xor(s2, off, 64);
      float rstd = 1.0f / sqrtf(s2 * (1.0f / 64.0f) + 1e-5f);
      float fin = dv * rstd * g1l + b1l;
      pf[rl][lane] = fin;
      fbuf[rl][lane] = (h16)fin;
    }
  }
  __syncthreads();

  // ---- step 5: o2 = fin @ fc_w^T + fcB
  {
    const h16* Bp = &fbuf[half][quad * 8];
    f16x8 b0 = *(const f16x8*)(Bp);
    f16x8 b1f = *(const f16x8*)(Bp + 32);
    f32x4 acc = {0.f, 0.f, 0.f, 0.f};
    const h16* Wp = WFb + (size_t)(wv * 16 + half) * 64 + quad * 8;
    acc = __builtin_amdgcn_mfma_f32_16x16x32_f16(*(const f16x8*)(Wp), b0, acc, 0, 0, 0);
    acc = __builtin_amdgcn_mfma_f32_16x16x32_f16(*(const f16x8*)(Wp + 32), b1f, acc, 0, 0, 0);
    int j = wv * 16 + quad * 4;
    float4 b4 = *(const float4*)(fcB + j);
    f16x4 o;
    o[0] = (h16)(acc[0] + b4.x); o[1] = (h16)(acc[1] + b4.y);
    o[2] = (h16)(acc[2] + b4.z); o[3] = (h16)(acc[3] + b4.w);
    *(f16x4*)(&tbuf[half][j]) = o;
  }
  __syncthreads();

  // ---- step 6: LN2 per r -> global out
  {
    float w3l = w3[lane], w4l = w4[lane];
    float g2l = g2[lane], b2l = b2[lane];
    #pragma unroll
    for (int i = 0; i < 4; ++i) {
      int rl = wv * 4 + i;
      float fin = pf[rl][lane];
      float oo = (float)tbuf[rl][lane];
      float pre = w3l * fin + w4l * oo;
      float s1 = pre;
      #pragma unroll
      for (int off = 32; off >= 1; off >>= 1) s1 += __shfl_xor(s1, off, 64);
      float mu = s1 * (1.0f / 64.0f);
      float dv = pre - mu;
      float s2 = dv * dv;
      #pragma unroll
      for (int off = 32; off >= 1; off >>= 1) s2 += __shfl_xor(s2, off, 64);
      float rstd = 1.0f / sqrtf(s2 * (1.0f / 64.0f) + 1e-5f);
      outp[(size_t)(blockIdx.x * 16 + rl) * 64 + lane] = dv * rstd * g2l + b2l;
    }
  }
}

}  // namespace

extern "C" void kernel_launch(void* const* d_in, const int* in_sizes, int n_in,
                              void* d_out, int out_size, void* d_ws, size_t ws_size,
                              hipStream_t stream) {
  const float* x      = (const float*)d_in[0];
  const int*   ei     = (const int*)d_in[1];
  const float* ew     = (const float*)d_in[2];
  const int*   gidx   = (const int*)d_in[3];
  const float* gcn1_w = (const float*)d_in[4];
  const float* gcn1_b = (const float*)d_in[5];
  const float* gcn2_w = (const float*)d_in[6];
  const float* gcn2_b = (const float*)d_in[7];
  const float* in_w   = (const float*)d_in[8];
  const float* in_b   = (const float*)d_in[9];
  const float* out_w  = (const float*)d_in[10];
  const float* out_b  = (const float*)d_in[11];
  const float* w1     = (const float*)d_in[12];
  const float* w2     = (const float*)d_in[13];
  const float* w3     = (const float*)d_in[14];
  const float* w4     = (const float*)d_in[15];
  const float* ln1_g  = (const float*)d_in[16];
  const float* ln1_b  = (const float*)d_in[17];
  const float* ln2_g  = (const float*)d_in[18];
  const float* ln2_b  = (const float*)d_in[19];
  const float* fc_w   = (const float*)d_in[20];
  const float* fc_b   = (const float*)d_in[21];
  float* outp = (float*)d_out;

  char* ws = (char*)d_ws;
  size_t off = 0;
  auto alloc = [&](size_t bytes) {
    void* p = ws + off;
    off += (bytes + 255) & ~(size_t)255;
    return p;
  };
  // persistent region
  h16* h1te = (h16*)alloc(sizeof(h16) * (size_t)T * N * D);  // h1 / time_embeds
  h16* Wb   = (h16*)alloc(sizeof(h16) * 32768);
  // union region: graph-prep buffers (pu aliased by hw)
  float* dinv   = (float*)alloc(sizeof(float) * T * N);
  int*   cnt    = (int*)alloc(sizeof(int) * T * N);
  int*   rowptr = (int*)alloc(sizeof(int) * T * N);
  int2*  pk     = (int2*)alloc(sizeof(int2) * (size_t)T * E);
  size_t pu_off = off;
  unsigned* pu  = (unsigned*)alloc(sizeof(unsigned) * (size_t)T * NR * SEG * BINS);  // 65.5 MB
  // hw aliases pu (pu dead after k_fill2; hw first written at GCN1 k_mm)
  h16* hw = (h16*)(ws + pu_off);
  size_t hw_end = pu_off + sizeof(h16) * (size_t)T * N * D;
  if (hw_end > off) off = hw_end;

  const h16* W1b = Wb;           // gcn1_w  [64][128]
  const h16* W2b = Wb + 8192;    // gcn2_w  [64][64]
  const h16* WIb = Wb + 12288;   // in_w    [192][64]
  const h16* WOb = Wb + 24576;   // out_w   [64][64]
  const h16* WFb = Wb + 28672;   // fc_w    [64][64]

  const int M = T * N;
  const int MW = M / 16;   // 31250
  const int PREP_BLOCKS = T * NR * SEG;  // 1000

  // graph prep — no global atomics
  k_hist<<<PREP_BLOCKS, 256, 0, stream>>>(ei, ew, pu);
  k_hreduce<<<(T * N + 255) / 256, 256, 0, stream>>>(pu, cnt, dinv);
  k_scan<<<T, 256, 0, stream>>>(cnt, rowptr);
  k_segoff<<<(T * N + 255) / 256, 256, 0, stream>>>(pu, rowptr);
  k_fill2<<<PREP_BLOCKS, 256, 0, stream>>>(ei, ew, pu, pk);
  k_prep<<<128, 256, 0, stream>>>(gcn1_w, gcn2_w, in_w, out_w, fc_w, Wb);

  // GCN stage (hw rows pre-scaled by dinv via MODE 2)
  dim3 gg(N / 8, T);
  k_mm<DIN, 4, false, 2><<<(MW + 3) / 4, 256, 0, stream>>>(W1b, x, dinv, hw, MW);
  k_gather<false><<<gg, 256, 0, stream>>>(hw, pk, dinv, rowptr, cnt, gcn1_b, nullptr, h1te);
  k_mm<D, 4, true, 2><<<(MW + 3) / 4, 256, 0, stream>>>(W2b, h1te, dinv, hw, MW);
  k_gather<true><<<gg, 256, 0, stream>>>(hw, pk, dinv, rowptr, cnt, gcn2_b, gidx, h1te);

  // fused attention tail: qkv + attn + out_proj + ln1 + fc + ln2
  k_tail<<<R / 16, 256, 0, stream>>>(h1te, WIb, in_b, WOb, out_b, WFb, fc_b,
                                     w1, w2, w3, w4, ln1_g, ln1_b, ln2_g, ln2_b, outp);
}

// Round 5
// 977.979 us; speedup vs baseline: 1.6396x; 1.0079x over previous
//
#include <hip/hip_runtime.h>
#include <cstdint>
#include <cstddef>

namespace {

constexpr int T = 10;
constexpr int N = 50000;
constexpr int R = 50000;
constexpr int DIN = 128;
constexpr int D = 64;
constexpr int E = 400000;

// LDS-binned edge-prep geometry
constexpr int BINS = 16384;             // bins per range (64 KB packed LDS)
constexpr int NR = 4;                   // ranges: 4*16384 = 65536 >= N
constexpr int SEG = 25;                 // edge segments per t (1000 blocks total)
constexpr int ESEG = E / SEG;           // 16000 edges per segment
constexpr int EV4 = ESEG / 4;           // 4000 int4 groups per segment

// hist packing: count in bits [24..31], weight-sum fixed-point 2^-18 in bits [0..23]
constexpr float WSCALE = 262144.0f;     // 2^18
constexpr float WINV = 1.0f / 262144.0f;

typedef _Float16 h16;
typedef __attribute__((ext_vector_type(8))) _Float16 f16x8;
typedef __attribute__((ext_vector_type(4))) _Float16 f16x4;
typedef __attribute__((ext_vector_type(4))) float f32x4;

// ---------------------------------------------------------------- pass A: LDS histogram (packed u32)
__global__ __launch_bounds__(256) void k_hist(const int* __restrict__ ei,
                                              const float* __restrict__ ew,
                                              unsigned* __restrict__ pu) {
  __shared__ unsigned h[BINS];  // 64 KB
  int b = blockIdx.x;
  int s = b % SEG;
  int tr = b / SEG;
  int r = tr % NR;
  int t = tr / NR;
  for (int i = threadIdx.x; i < BINS; i += 256) h[i] = 0u;
  __syncthreads();
  int bin0 = r * BINS;
  const int4* dst4 = (const int4*)(ei + (size_t)t * 2 * E + E + s * ESEG);
  const float4* ew4 = (const float4*)(ew + (size_t)t * E + s * ESEG);
  for (int i = threadIdx.x; i < EV4; i += 256) {
    int4 d = dst4[i];
    float4 w = ew4[i];
    unsigned a0 = (unsigned)(d.x - bin0);
    unsigned a1 = (unsigned)(d.y - bin0);
    unsigned a2 = (unsigned)(d.z - bin0);
    unsigned a3 = (unsigned)(d.w - bin0);
    if (a0 < (unsigned)BINS) atomicAdd(&h[a0], 0x1000000u + (unsigned)fmaf(w.x, WSCALE, 0.5f));
    if (a1 < (unsigned)BINS) atomicAdd(&h[a1], 0x1000000u + (unsigned)fmaf(w.y, WSCALE, 0.5f));
    if (a2 < (unsigned)BINS) atomicAdd(&h[a2], 0x1000000u + (unsigned)fmaf(w.z, WSCALE, 0.5f));
    if (a3 < (unsigned)BINS) atomicAdd(&h[a3], 0x1000000u + (unsigned)fmaf(w.w, WSCALE, 0.5f));
  }
  __syncthreads();
  size_t base = (size_t)b * BINS;
  for (int i = threadIdx.x; i < BINS; i += 256) pu[base + i] = h[i];
}

// ---------------------------------------------------------------- pass B (fused): partials -> cnt, dinv, rowptr (atomic base), seg cursors
// One block = 256 nodes of one t. Block shuffle-scan of cnt + one atomicAdd on
// tbase[t] gives each node a unique CSR region (order across blocks arbitrary —
// harmless). Per-seg counts kept in registers -> cursors written in place,
// absorbing the old k_scan + k_segoff passes.
__global__ __launch_bounds__(256) void k_hreduce2(unsigned* __restrict__ pu,
                                                  int* __restrict__ cnt,
                                                  float* __restrict__ dinv,
                                                  int* __restrict__ rowptr,
                                                  int* __restrict__ tbase) {
  int t = blockIdx.y;
  int n = blockIdx.x * 256 + threadIdx.x;
  int lane = threadIdx.x & 63, wid = threadIdx.x >> 6;
  __shared__ int wsum[4];
  __shared__ int base_s;
  unsigned cs[SEG];
  unsigned c = 0, wacc = 0;
  bool ok = (n < N);
  int r = 0, rel = 0;
  if (ok) {
    r = n / BINS; rel = n - r * BINS;
    #pragma unroll
    for (int s = 0; s < SEG; ++s) {
      unsigned v = pu[((size_t)((t * NR + r) * SEG + s)) * BINS + rel];
      cs[s] = v >> 24;
      c += cs[s];
      wacc += v & 0xFFFFFFu;
    }
    cnt[t * N + n] = (int)c;
    dinv[t * N + n] = rsqrtf(1.0f + (float)wacc * WINV);  // deg = 1 (self) + sum(ew)
  }
  // block exclusive scan of c
  int sv = (int)c;
  #pragma unroll
  for (int off = 1; off < 64; off <<= 1) {
    int u = __shfl_up(sv, off, 64);
    if (lane >= off) sv += u;
  }
  if (lane == 63) wsum[wid] = sv;
  __syncthreads();
  int wadd = 0;
  #pragma unroll
  for (int w = 0; w < 4; ++w) if (w < wid) wadd += wsum[w];
  if (threadIdx.x == 255) base_s = atomicAdd(&tbase[t], wadd + sv);
  __syncthreads();
  if (ok) {
    unsigned run = (unsigned)(base_s + wadd + sv - (int)c);
    rowptr[t * N + n] = (int)run;
    #pragma unroll
    for (int s = 0; s < SEG; ++s) {
      size_t b = ((size_t)((t * NR + r) * SEG + s)) * BINS + rel;
      pu[b] = run;
      run += cs[s];
    }
  }
}

// ---------------------------------------------------------------- pass D: place packed (src, raw ew) via LDS cursors
__global__ __launch_bounds__(256) void k_fill2(const int* __restrict__ ei,
                                               const float* __restrict__ ew,
                                               const unsigned* __restrict__ pu,
                                               int2* __restrict__ pk) {
  __shared__ int cur[BINS];  // 64 KB
  int b = blockIdx.x;
  int s = b % SEG;
  int tr = b / SEG;
  int r = tr % NR;
  int t = tr / NR;
  size_t pbase = (size_t)b * BINS;
  for (int i = threadIdx.x; i < BINS; i += 256) cur[i] = (int)pu[pbase + i];
  __syncthreads();
  int bin0 = r * BINS;
  const int4* src4 = (const int4*)(ei + (size_t)t * 2 * E + s * ESEG);
  const int4* dst4 = (const int4*)(ei + (size_t)t * 2 * E + E + s * ESEG);
  const float4* ew4 = (const float4*)(ew + (size_t)t * E + s * ESEG);
  int2* pkt = pk + (size_t)t * E;
  for (int i = threadIdx.x; i < EV4; i += 256) {
    int4 d = dst4[i];
    int4 sv = src4[i];
    float4 w = ew4[i];
    unsigned a0 = (unsigned)(d.x - bin0);
    unsigned a1 = (unsigned)(d.y - bin0);
    unsigned a2 = (unsigned)(d.z - bin0);
    unsigned a3 = (unsigned)(d.w - bin0);
    if (a0 < (unsigned)BINS) {
      int pos = atomicAdd(&cur[a0], 1);
      pkt[pos] = make_int2(sv.x, __float_as_int(w.x));
    }
    if (a1 < (unsigned)BINS) {
      int pos = atomicAdd(&cur[a1], 1);
      pkt[pos] = make_int2(sv.y, __float_as_int(w.y));
    }
    if (a2 < (unsigned)BINS) {
      int pos = atomicAdd(&cur[a2], 1);
      pkt[pos] = make_int2(sv.z, __float_as_int(w.z));
    }
    if (a3 < (unsigned)BINS) {
      int pos = atomicAdd(&cur[a3], 1);
      pkt[pos] = make_int2(sv.w, __float_as_int(w.w));
    }
  }
}

// ---------------------------------------------------------------- weight prep: fp32 -> fp16 + zero tbase
__global__ __launch_bounds__(256) void k_prep(const float* __restrict__ g1w,
                                              const float* __restrict__ g2w,
                                              const float* __restrict__ inw,
                                              const float* __restrict__ outw,
                                              const float* __restrict__ fcw,
                                              h16* __restrict__ Wb,
                                              int* __restrict__ tbase) {
  int i = blockIdx.x * 256 + threadIdx.x;
  if (i >= 32768) {
    if (i < 32768 + 16) tbase[i - 32768] = 0;
    return;
  }
  const float* src;
  int off;
  if (i < 8192)       { src = g1w;  off = 0; }
  else if (i < 12288) { src = g2w;  off = 8192; }
  else if (i < 24576) { src = inw;  off = 12288; }
  else if (i < 28672) { src = outw; off = 24576; }
  else                { src = fcw;  off = 28672; }
  Wb[i] = (h16)src[i - off];
}

// ---------------------------------------------------------------- MFMA GEMM: out[m][j] = sum_k W[j][k] * B[m][k]
// C/D layout (16x16x32): col = lane&15 -> m; row = quad*4+reg -> j.
// MODE 0: plain f16 out.  MODE 2: row-scale by biasp[m] (dinv).
template <int K, int NT, bool F16B, int MODE>
__global__ __launch_bounds__(256) void k_mm(const h16* __restrict__ Wb,
                                            const void* __restrict__ Bv,
                                            const float* __restrict__ biasp,
                                            h16* __restrict__ out,
                                            int Mwaves) {
  int wv = threadIdx.x >> 6, lane = threadIdx.x & 63;
  int wave = blockIdx.x * 4 + wv;
  if (wave >= Mwaves) return;
  int m0 = wave * 16;
  int half = lane & 15, quad = lane >> 4;
  constexpr int KS = K / 32;
  int m = m0 + half;
  float ds = 1.0f;
  if (MODE == 2) ds = biasp[m];
  f16x8 bfrag[KS];
  if (F16B) {
    const h16* Bp = (const h16*)Bv + (size_t)m * K + quad * 8;
    #pragma unroll
    for (int ks = 0; ks < KS; ++ks) bfrag[ks] = *(const f16x8*)(Bp + ks * 32);
  } else {
    const float* Bp = (const float*)Bv + (size_t)m * K + quad * 8;
    #pragma unroll
    for (int ks = 0; ks < KS; ++ks) {
      float4 f0 = *(const float4*)(Bp + ks * 32);
      float4 f1 = *(const float4*)(Bp + ks * 32 + 4);
      f16x8 b;
      b[0] = (h16)f0.x; b[1] = (h16)f0.y; b[2] = (h16)f0.z; b[3] = (h16)f0.w;
      b[4] = (h16)f1.x; b[5] = (h16)f1.y; b[6] = (h16)f1.z; b[7] = (h16)f1.w;
      bfrag[ks] = b;
    }
  }
  #pragma unroll
  for (int jt = 0; jt < NT; ++jt) {
    f32x4 acc = {0.f, 0.f, 0.f, 0.f};
    const h16* Wp = Wb + (size_t)(jt * 16 + half) * K + quad * 8;
    #pragma unroll
    for (int ks = 0; ks < KS; ++ks) {
      f16x8 afrag = *(const f16x8*)(Wp + ks * 32);
      acc = __builtin_amdgcn_mfma_f32_16x16x32_f16(afrag, bfrag[ks], acc, 0, 0, 0);
    }
    int j = jt * 16 + quad * 4;
    if (MODE == 2) {
      acc[0] *= ds; acc[1] *= ds; acc[2] *= ds; acc[3] *= ds;
    }
    f16x4 o;
    o[0] = (h16)acc[0]; o[1] = (h16)acc[1]; o[2] = (h16)acc[2]; o[3] = (h16)acc[3];
    *(f16x4*)(out + (size_t)m * (NT * 16) + j) = o;
  }
}

// ---------------------------------------------------------------- GCN aggregation (gather over CSR)
// 2 nodes per wave, 4 groups x 8 lanes per node; each lane covers 8 features
// (16B f16 loads). Quad-unrolled edge loop: 4 recs + 4 rows in flight per group
// (16 dependent chains per wave) to cover L2/L3 latency.
template <bool SCATTER>
__global__ __launch_bounds__(256) void k_gather(
    const h16* __restrict__ hw, const int2* __restrict__ pk,
    const float* __restrict__ dinv, const int* __restrict__ rowptr,
    const int* __restrict__ cnt, const float* __restrict__ bias,
    const int* __restrict__ gidx, h16* __restrict__ outp) {
  __shared__ __align__(16) float red[4][8][68];  // [wave][nd*4+grp][feat pad+4]
  int wv = threadIdx.x >> 6, lane = threadIdx.x & 63;
  int t = blockIdx.y;
  int nd = lane >> 5;            // which of the 2 nodes
  int grp = (lane >> 3) & 3;     // 4 edge-groups per node
  int sub = lane & 7;            // 8 feature-lanes per group
  int n = blockIdx.x * 8 + wv * 2 + nd;
  const h16* hwt = hw + (size_t)t * N * D;
  const int2* pkt = pk + (size_t)t * E;
  int start = rowptr[t * N + n];
  int m = cnt[t * N + n];
  // hoist independent epilogue loads (lane = feature for node nA/nB)
  int nA = blockIdx.x * 8 + wv * 2;
  int nB = nA + 1;
  float selfA = (float)hwt[(size_t)nA * D + lane];
  float selfB = (float)hwt[(size_t)nB * D + lane];
  float dnA = dinv[t * N + nA];
  float dnB = dinv[t * N + nB];
  float bi = bias[lane];
  f32x4 accL = {0.f, 0.f, 0.f, 0.f};
  f32x4 accH = {0.f, 0.f, 0.f, 0.f};
  int e = grp;
  for (; e + 12 < m; e += 16) {
    int2 r0 = pkt[start + e];
    int2 r1 = pkt[start + e + 4];
    int2 r2 = pkt[start + e + 8];
    int2 r3 = pkt[start + e + 12];
    float w0 = __int_as_float(r0.y);
    float w1 = __int_as_float(r1.y);
    float w2 = __int_as_float(r2.y);
    float w3 = __int_as_float(r3.y);
    f16x8 h0 = *(const f16x8*)(hwt + (size_t)r0.x * D + sub * 8);
    f16x8 h1 = *(const f16x8*)(hwt + (size_t)r1.x * D + sub * 8);
    f16x8 h2 = *(const f16x8*)(hwt + (size_t)r2.x * D + sub * 8);
    f16x8 h3 = *(const f16x8*)(hwt + (size_t)r3.x * D + sub * 8);
    #pragma unroll
    for (int j = 0; j < 4; ++j) {
      accL[j] = fmaf(w0, (float)h0[j], accL[j]);
      accH[j] = fmaf(w0, (float)h0[j + 4], accH[j]);
    }
    #pragma unroll
    for (int j = 0; j < 4; ++j) {
      accL[j] = fmaf(w1, (float)h1[j], accL[j]);
      accH[j] = fmaf(w1, (float)h1[j + 4], accH[j]);
    }
    #pragma unroll
    for (int j = 0; j < 4; ++j) {
      accL[j] = fmaf(w2, (float)h2[j], accL[j]);
      accH[j] = fmaf(w2, (float)h2[j + 4], accH[j]);
    }
    #pragma unroll
    for (int j = 0; j < 4; ++j) {
      accL[j] = fmaf(w3, (float)h3[j], accL[j]);
      accH[j] = fmaf(w3, (float)h3[j + 4], accH[j]);
    }
  }
  for (; e + 4 < m; e += 8) {
    int2 ra = pkt[start + e];
    int2 rb = pkt[start + e + 4];
    float wa = __int_as_float(ra.y);
    float wb = __int_as_float(rb.y);
    f16x8 ha = *(const f16x8*)(hwt + (size_t)ra.x * D + sub * 8);
    f16x8 hb = *(const f16x8*)(hwt + (size_t)rb.x * D + sub * 8);
    #pragma unroll
    for (int j = 0; j < 4; ++j) {
      accL[j] = fmaf(wa, (float)ha[j], accL[j]);
      accH[j] = fmaf(wa, (float)ha[j + 4], accH[j]);
    }
    #pragma unroll
    for (int j = 0; j < 4; ++j) {
      accL[j] = fmaf(wb, (float)hb[j], accL[j]);
      accH[j] = fmaf(wb, (float)hb[j + 4], accH[j]);
    }
  }
  if (e < m) {
    int2 ra = pkt[start + e];
    float wa = __int_as_float(ra.y);
    f16x8 ha = *(const f16x8*)(hwt + (size_t)ra.x * D + sub * 8);
    #pragma unroll
    for (int j = 0; j < 4; ++j) {
      accL[j] = fmaf(wa, (float)ha[j], accL[j]);
      accH[j] = fmaf(wa, (float)ha[j + 4], accH[j]);
    }
  }
  // wave-synchronous LDS reduce across the 4 groups of each node
  float* rw = &red[wv][nd * 4 + grp][sub * 8];
  *(f32x4*)(rw) = accL;
  *(f32x4*)(rw + 4) = accH;
  __builtin_amdgcn_wave_barrier();
  // epilogue: lane owns feature `lane`, loops over the 2 nodes
  #pragma unroll
  for (int d2 = 0; d2 < 2; ++d2) {
    int nn = nA + d2;
    float s = red[wv][d2 * 4 + 0][lane] + red[wv][d2 * 4 + 1][lane] +
              red[wv][d2 * 4 + 2][lane] + red[wv][d2 * 4 + 3][lane];
    float selfv = d2 ? selfB : selfA;
    float dn = d2 ? dnB : dnA;
    float v = fmaxf(fmaf(dn, s + selfv, bi), 0.f);
    size_t ro;
    if (SCATTER) {
      int rr2 = gidx[(size_t)t * R + nn];
      ro = ((size_t)rr2 * T + t) * D + lane;
    } else {
      ro = ((size_t)t * N + nn) * D + lane;
    }
    outp[ro] = (h16)v;
  }
}

// ---------------------------------------------------------------- fused attention tail
// One block = 16 r's (160 te rows). qkv MFMA -> LDS, attention, out_proj MFMA,
// LN1, fc MFMA, LN2 -> global f32 out. kv never touches global memory.
constexpr int KVP = 132;   // kv row pad (f16) -> 264 B rows, 2-way bank spread
constexpr int P72 = 72;    // 16-row tile pad  -> 144 B rows, 16B-aligned

__global__ __launch_bounds__(256) void k_tail(
    const h16* __restrict__ te,      // [R*T][64] f16
    const h16* __restrict__ WIb,     // in_proj [192][64]
    const float* __restrict__ inB,
    const h16* __restrict__ WOb,     // out_proj [64][64]
    const float* __restrict__ outB,
    const h16* __restrict__ WFb,     // fc [64][64]
    const float* __restrict__ fcB,
    const float* __restrict__ w1,
    const float* __restrict__ w2,
    const float* __restrict__ w3,
    const float* __restrict__ w4,
    const float* __restrict__ g1, const float* __restrict__ b1,
    const float* __restrict__ g2, const float* __restrict__ b2,
    float* __restrict__ outp) {
  __shared__ __align__(16) h16 kvl[160][KVP];   // k cols 0..63, v cols 64..127
  __shared__ __align__(16) h16 ql[16][P72];
  __shared__ __align__(16) h16 aol[16][P72];
  __shared__ __align__(16) h16 tbuf[16][P72];   // proj, then o2
  __shared__ __align__(16) h16 fbuf[16][P72];   // finb
  __shared__ __align__(16) float pf[16][64];    // fin f32

  int wv = threadIdx.x >> 6, lane = threadIdx.x & 63;
  int half = lane & 15, quad = lane >> 4;
  int g0 = blockIdx.x * 160;  // first global te row (r0*T)

  // ---- step 1: qkv = te @ in_w^T (+b) into LDS
  for (int tt = wv; tt < 10; tt += 4) {
    int lr = tt * 16 + half;  // local row 0..159
    const h16* Bp = te + (size_t)(g0 + lr) * 64 + quad * 8;
    f16x8 b0 = *(const f16x8*)(Bp);
    f16x8 b1f = *(const f16x8*)(Bp + 32);
    int rloc = lr / 10;
    bool isq = (lr - rloc * 10) == 9;
    #pragma unroll
    for (int jt = 0; jt < 12; ++jt) {
      f32x4 acc = {0.f, 0.f, 0.f, 0.f};
      const h16* Wp = WIb + (size_t)(jt * 16 + half) * 64 + quad * 8;
      acc = __builtin_amdgcn_mfma_f32_16x16x32_f16(*(const f16x8*)(Wp), b0, acc, 0, 0, 0);
      acc = __builtin_amdgcn_mfma_f32_16x16x32_f16(*(const f16x8*)(Wp + 32), b1f, acc, 0, 0, 0);
      int j = jt * 16 + quad * 4;
      float4 b4 = *(const float4*)(inB + j);
      f16x4 o;
      o[0] = (h16)(acc[0] + b4.x); o[1] = (h16)(acc[1] + b4.y);
      o[2] = (h16)(acc[2] + b4.z); o[3] = (h16)(acc[3] + b4.w);
      if (jt < 4) {
        if (isq) *(f16x4*)(&ql[rloc][j]) = o;
      } else {
        *(f16x4*)(&kvl[lr][j - 64]) = o;
      }
    }
  }
  __syncthreads();

  // ---- step 2: attention (one wave per r, 4 rounds); lane = feature
  #pragma unroll
  for (int i = 0; i < 4; ++i) {
    int rl = wv * 4 + i;
    float qv = (float)ql[rl][lane];
    float sc[T], vv[T];
    #pragma unroll
    for (int s = 0; s < T; ++s) {
      float kk = (float)kvl[rl * 10 + s][lane];
      vv[s] = (float)kvl[rl * 10 + s][64 + lane];
      float p = qv * kk;
      p += __shfl_xor(p, 8, 16);
      p += __shfl_xor(p, 4, 16);
      p += __shfl_xor(p, 2, 16);
      p += __shfl_xor(p, 1, 16);
      sc[s] = p * 0.25f;  // 1/sqrt(16)
    }
    float mx = sc[0];
    #pragma unroll
    for (int s = 1; s < T; ++s) mx = fmaxf(mx, sc[s]);
    float ssum = 0.f;
    #pragma unroll
    for (int s = 0; s < T; ++s) { sc[s] = expf(sc[s] - mx); ssum += sc[s]; }
    float rinv = 1.0f / ssum;
    float aov = 0.f;
    #pragma unroll
    for (int s = 0; s < T; ++s) aov = fmaf(sc[s] * rinv, vv[s], aov);
    aol[rl][lane] = (h16)aov;
  }
  __syncthreads();

  // ---- step 3: proj = ao @ out_w^T + outB (one 16x64 tile; wave wv owns jt=wv)
  {
    const h16* Bp = &aol[half][quad * 8];
    f16x8 b0 = *(const f16x8*)(Bp);
    f16x8 b1f = *(const f16x8*)(Bp + 32);
    f32x4 acc = {0.f, 0.f, 0.f, 0.f};
    const h16* Wp = WOb + (size_t)(wv * 16 + half) * 64 + quad * 8;
    acc = __builtin_amdgcn_mfma_f32_16x16x32_f16(*(const f16x8*)(Wp), b0, acc, 0, 0, 0);
    acc = __builtin_amdgcn_mfma_f32_16x16x32_f16(*(const f16x8*)(Wp + 32), b1f, acc, 0, 0, 0);
    int j = wv * 16 + quad * 4;
    float4 b4 = *(const float4*)(outB + j);
    f16x4 o;
    o[0] = (h16)(acc[0] + b4.x); o[1] = (h16)(acc[1] + b4.y);
    o[2] = (h16)(acc[2] + b4.z); o[3] = (h16)(acc[3] + b4.w);
    *(f16x4*)(&tbuf[half][j]) = o;
  }
  __syncthreads();

  // ---- step 4: LN1 per r (one wave per r, 4 rounds)
  {
    float w1l = w1[(T - 1) * 64 + lane];
    float w2l = w2[(T - 1) * 64 + lane];
    float g1l = g1[lane], b1l = b1[lane];
    #pragma unroll
    for (int i = 0; i < 4; ++i) {
      int rl = wv * 4 + i;
      float t9 = (float)te[(size_t)(g0 + rl * 10 + 9) * 64 + lane];
      float pr = (float)tbuf[rl][lane];
      float pre = w1l * t9 + w2l * pr;
      float s1 = pre;
      #pragma unroll
      for (int off = 32; off >= 1; off >>= 1) s1 += __shfl_xor(s1, off, 64);
      float mu = s1 * (1.0f / 64.0f);
      float dv = pre - mu;
      float s2 = dv * dv;
      #pragma unroll
      for (int off = 32; off >= 1; off >>= 1) s2 += __shfl_xor(s2, off, 64);
      float rstd = 1.0f / sqrtf(s2 * (1.0f / 64.0f) + 1e-5f);
      float fin = dv * rstd * g1l + b1l;
      pf[rl][lane] = fin;
      fbuf[rl][lane] = (h16)fin;
    }
  }
  __syncthreads();

  // ---- step 5: o2 = fin @ fc_w^T + fcB
  {
    const h16* Bp = &fbuf[half][quad * 8];
    f16x8 b0 = *(const f16x8*)(Bp);
    f16x8 b1f = *(const f16x8*)(Bp + 32);
    f32x4 acc = {0.f, 0.f, 0.f, 0.f};
    const h16* Wp = WFb + (size_t)(wv * 16 + half) * 64 + quad * 8;
    acc = __builtin_amdgcn_mfma_f32_16x16x32_f16(*(const f16x8*)(Wp), b0, acc, 0, 0, 0);
    acc = __builtin_amdgcn_mfma_f32_16x16x32_f16(*(const f16x8*)(Wp + 32), b1f, acc, 0, 0, 0);
    int j = wv * 16 + quad * 4;
    float4 b4 = *(const float4*)(fcB + j);
    f16x4 o;
    o[0] = (h16)(acc[0] + b4.x); o[1] = (h16)(acc[1] + b4.y);
    o[2] = (h16)(acc[2] + b4.z); o[3] = (h16)(acc[3] + b4.w);
    *(f16x4*)(&tbuf[half][j]) = o;
  }
  __syncthreads();

  // ---- step 6: LN2 per r -> global out
  {
    float w3l = w3[lane], w4l = w4[lane];
    float g2l = g2[lane], b2l = b2[lane];
    #pragma unroll
    for (int i = 0; i < 4; ++i) {
      int rl = wv * 4 + i;
      float fin = pf[rl][lane];
      float oo = (float)tbuf[rl][lane];
      float pre = w3l * fin + w4l * oo;
      float s1 = pre;
      #pragma unroll
      for (int off = 32; off >= 1; off >>= 1) s1 += __shfl_xor(s1, off, 64);
      float mu = s1 * (1.0f / 64.0f);
      float dv = pre - mu;
      float s2 = dv * dv;
      #pragma unroll
      for (int off = 32; off >= 1; off >>= 1) s2 += __shfl_xor(s2, off, 64);
      float rstd = 1.0f / sqrtf(s2 * (1.0f / 64.0f) + 1e-5f);
      outp[(size_t)(blockIdx.x * 16 + rl) * 64 + lane] = dv * rstd * g2l + b2l;
    }
  }
}

}  // namespace

extern "C" void kernel_launch(void* const* d_in, const int* in_sizes, int n_in,
                              void* d_out, int out_size, void* d_ws, size_t ws_size,
                              hipStream_t stream) {
  const float* x      = (const float*)d_in[0];
  const int*   ei     = (const int*)d_in[1];
  const float* ew     = (const float*)d_in[2];
  const int*   gidx   = (const int*)d_in[3];
  const float* gcn1_w = (const float*)d_in[4];
  const float* gcn1_b = (const float*)d_in[5];
  const float* gcn2_w = (const float*)d_in[6];
  const float* gcn2_b = (const float*)d_in[7];
  const float* in_w   = (const float*)d_in[8];
  const float* in_b   = (const float*)d_in[9];
  const float* out_w  = (const float*)d_in[10];
  const float* out_b  = (const float*)d_in[11];
  const float* w1     = (const float*)d_in[12];
  const float* w2     = (const float*)d_in[13];
  const float* w3     = (const float*)d_in[14];
  const float* w4     = (const float*)d_in[15];
  const float* ln1_g  = (const float*)d_in[16];
  const float* ln1_b  = (const float*)d_in[17];
  const float* ln2_g  = (const float*)d_in[18];
  const float* ln2_b  = (const float*)d_in[19];
  const float* fc_w   = (const float*)d_in[20];
  const float* fc_b   = (const float*)d_in[21];
  float* outp = (float*)d_out;

  char* ws = (char*)d_ws;
  size_t off = 0;
  auto alloc = [&](size_t bytes) {
    void* p = ws + off;
    off += (bytes + 255) & ~(size_t)255;
    return p;
  };
  // persistent region
  h16* h1te = (h16*)alloc(sizeof(h16) * (size_t)T * N * D);  // h1 / time_embeds
  h16* Wb   = (h16*)alloc(sizeof(h16) * 32768);
  int* tbase = (int*)alloc(sizeof(int) * 16);
  // union region: graph-prep buffers (pu aliased by hw)
  float* dinv   = (float*)alloc(sizeof(float) * T * N);
  int*   cnt    = (int*)alloc(sizeof(int) * T * N);
  int*   rowptr = (int*)alloc(sizeof(int) * T * N);
  int2*  pk     = (int2*)alloc(sizeof(int2) * (size_t)T * E);
  size_t pu_off = off;
  unsigned* pu  = (unsigned*)alloc(sizeof(unsigned) * (size_t)T * NR * SEG * BINS);  // 65.5 MB
  // hw aliases pu (pu dead after k_fill2; hw first written at GCN1 k_mm)
  h16* hw = (h16*)(ws + pu_off);
  size_t hw_end = pu_off + sizeof(h16) * (size_t)T * N * D;
  if (hw_end > off) off = hw_end;

  const h16* W1b = Wb;           // gcn1_w  [64][128]
  const h16* W2b = Wb + 8192;    // gcn2_w  [64][64]
  const h16* WIb = Wb + 12288;   // in_w    [192][64]
  const h16* WOb = Wb + 24576;   // out_w   [64][64]
  const h16* WFb = Wb + 28672;   // fc_w    [64][64]

  const int M = T * N;
  const int MW = M / 16;   // 31250
  const int PREP_BLOCKS = T * NR * SEG;  // 1000

  // weight cvt + tbase zero first (independent of edge passes)
  k_prep<<<129, 256, 0, stream>>>(gcn1_w, gcn2_w, in_w, out_w, fc_w, Wb, tbase);

  // graph prep — LDS-binned, one block-atomic per 256 nodes
  k_hist<<<PREP_BLOCKS, 256, 0, stream>>>(ei, ew, pu);
  dim3 hg((N + 255) / 256, T);
  k_hreduce2<<<hg, 256, 0, stream>>>(pu, cnt, dinv, rowptr, tbase);
  k_fill2<<<PREP_BLOCKS, 256, 0, stream>>>(ei, ew, pu, pk);

  // GCN stage (hw rows pre-scaled by dinv via MODE 2)
  dim3 gg(N / 8, T);
  k_mm<DIN, 4, false, 2><<<(MW + 3) / 4, 256, 0, stream>>>(W1b, x, dinv, hw, MW);
  k_gather<false><<<gg, 256, 0, stream>>>(hw, pk, dinv, rowptr, cnt, gcn1_b, nullptr, h1te);
  k_mm<D, 4, true, 2><<<(MW + 3) / 4, 256, 0, stream>>>(W2b, h1te, dinv, hw, MW);
  k_gather<true><<<gg, 256, 0, stream>>>(hw, pk, dinv, rowptr, cnt, gcn2_b, gidx, h1te);

  // fused attention tail: qkv + attn + out_proj + ln1 + fc + ln2
  k_tail<<<R / 16, 256, 0, stream>>>(h1te, WIb, in_b, WOb, out_b, WFb, fc_b,
                                     w1, w2, w3, w4, ln1_g, ln1_b, ln2_g, ln2_b, outp);
}